// Round 1
// baseline (4993.422 us; speedup 1.0000x reference)
//
#include <hip/hip_runtime.h>
#include <math.h>

#define NXC 32768
#define NVC 16384
#define OUTWC (NXC + 64 + NVC)

static constexpr float DXf   = 1.0f/32768.0f;
static constexpr float DVf   = 16.0f/16384.0f;
static constexpr float DTf   = 1e-3f;
static constexpr float VMAXf = 8.0f;
static constexpr float INV2PI= 0.15915494309189535f;

#define PS_V 16576
#define PS_X 8256
#define PS_E 8192

// ---------------- gshape ----------------
__global__ __launch_bounds__(1024) void k_gshape(float* __restrict__ g){
  __shared__ float red[1024];
  int t = threadIdx.x;
  float s = 0.f;
  for (int i = t; i < NXC; i += 1024){
    float x = (i + 0.5f)*DXf - 0.5f;
    float xx = x*10.0f;
    float gv = expf(-0.5f*xx*xx);
    g[i] = gv; s += gv;
  }
  red[t] = s; __syncthreads();
  for (int o = 512; o > 0; o >>= 1){ if (t < o) red[t] += red[t+o]; __syncthreads(); }
  float norm = 1.0f/(red[0]*DXf);
  for (int i = t; i < NXC; i += 1024) g[i] *= norm;
}

// ---------------- V stats: G0, G1(lag), vpm, vmm, sV, VM, w ----------------
__global__ __launch_bounds__(256) void k_vstats(const float* __restrict__ V, float* __restrict__ part, float Amax){
  __shared__ float Vt[64][66];
  int blk = blockIdx.x;               // 64 blocks
  int chunk = NVC/64;                 // 256
  int c0b = blk*chunk;
  int tid = threadIdx.x;
  int ta = tid >> 4, tb = tid & 15;
  int a0 = ta*4, b0 = tb*4;
  float acc0[4][4]={{0}}, acc1[4][4]={{0}}, accp[4][4]={{0}}, accm[4][4]={{0}};
  float vsv[4]={0,0,0,0}, vvm[4]={0,0,0,0}, vwv[4]={0,0,0,0};
  float fm = sqrtf(Amax*INV2PI);
  for (int t0 = 0; t0 < chunk; t0 += 64){
    int c0 = c0b + t0;
    for (int i = tid; i < 64*65; i += 256){
      int r = i/65, cc = i%65;
      int c = c0 - 1 + cc;
      Vt[r][cc] = (c >= 0 && c < NVC) ? V[(size_t)r*NVC + c] : 0.f;
    }
    __syncthreads();
    for (int jj = 0; jj < 64; ++jj){
      int j = c0 + jj;
      float vs = -VMAXf + (j + 0.5f)*DVf;
      float wpj = (vs > 0.f ? vs : 0.f)*DVf;
      float wmj = (vs < 0.f ? vs : 0.f)*DVf;
      float av[4], bv[4], bm[4];
      #pragma unroll
      for (int k=0;k<4;k++){ av[k]=Vt[a0+k][jj+1]; bv[k]=Vt[b0+k][jj+1]; bm[k]=Vt[b0+k][jj]; }
      float lag = (j >= 1) ? 1.f : 0.f;
      #pragma unroll
      for (int ka=0;ka<4;ka++){
        #pragma unroll
        for (int kb=0;kb<4;kb++){
          float p = av[ka]*bv[kb];
          acc0[ka][kb] += p;
          accp[ka][kb] += p*wpj;
          accm[ka][kb] += p*wmj;
          acc1[ka][kb] += lag*av[ka]*bm[kb];
        }
      }
      if (tb == 0){
        float mv = fm*expf(-0.5f*Amax*vs*vs)*DVf;
        #pragma unroll
        for (int k=0;k<4;k++){
          vsv[k] += av[k];
          vvm[k] += av[k]*mv;
          vwv[k] += av[k]*wpj;
        }
      }
    }
    __syncthreads();
  }
  float* pb = part + (size_t)blk*PS_V;
  #pragma unroll
  for (int ka=0;ka<4;ka++){
    #pragma unroll
    for (int kb=0;kb<4;kb++){
      int idx = (a0+ka)*64 + (b0+kb);
      pb[idx]        = acc0[ka][kb];
      pb[4096+idx]   = acc1[ka][kb];
      pb[8192+idx]   = accp[ka][kb];
      pb[12288+idx]  = accm[ka][kb];
    }
  }
  if (tb == 0){
    #pragma unroll
    for (int k=0;k<4;k++){
      pb[16384 + a0+k] = vsv[k];
      pb[16448 + a0+k] = vvm[k];
      pb[16512 + a0+k] = vwv[k];
    }
  }
}

// ---------------- X stats: G, H(lag), XG ----------------
__global__ __launch_bounds__(256) void k_xstats(const float* __restrict__ X, int pitch,
                                                const float* __restrict__ gsh, float* __restrict__ part){
  __shared__ float Xt[64][66];
  int blk = blockIdx.x;               // 128 blocks
  int chunk = NXC/128;                // 256
  int c0b = blk*chunk;
  int tid = threadIdx.x, ta = tid>>4, tb = tid&15, a0 = ta*4, b0 = tb*4;
  float accg[4][4]={{0}}, acch[4][4]={{0}};
  float axg[4]={0,0,0,0};
  for (int t0=0;t0<chunk;t0+=64){
    int c0 = c0b+t0;
    for (int i=tid;i<64*65;i+=256){
      int r=i/65, cc=i%65; int x=c0-1+cc;
      Xt[r][cc] = (x>=0 && x<NXC) ? X[(size_t)r*pitch + x] : 0.f;
    }
    __syncthreads();
    for (int jj=0;jj<64;jj++){
      int x = c0+jj;
      float av[4],bv[4],bm[4];
      #pragma unroll
      for (int k=0;k<4;k++){ av[k]=Xt[a0+k][jj+1]; bv[k]=Xt[b0+k][jj+1]; bm[k]=Xt[b0+k][jj]; }
      float lag = (x>=1)?1.f:0.f;
      #pragma unroll
      for (int ka=0;ka<4;ka++){
        #pragma unroll
        for (int kb=0;kb<4;kb++){
          accg[ka][kb] += av[ka]*bv[kb];
          acch[ka][kb] += lag*av[ka]*bm[kb];
        }
      }
      if (tb==0){
        float gw = gsh[x]*DXf;
        #pragma unroll
        for (int k=0;k<4;k++) axg[k] += av[k]*gw;
      }
    }
    __syncthreads();
  }
  float* pb = part + (size_t)blk*PS_X;
  #pragma unroll
  for (int ka=0;ka<4;ka++){
    #pragma unroll
    for (int kb=0;kb<4;kb++){
      int idx = (a0+ka)*64 + (b0+kb);
      pb[idx] = accg[ka][kb];
      pb[4096+idx] = acch[ka][kb];
    }
  }
  if (tb==0){
    #pragma unroll
    for (int k=0;k<4;k++) pb[8192 + a0+k] = axg[k];
  }
}

// ---------------- E-weighted grams: Epm, Emm ----------------
__global__ __launch_bounds__(256) void k_eweight(const float* __restrict__ X, int pitch,
                                                 const float* __restrict__ E, float fac, float* __restrict__ part){
  __shared__ float Xt[64][65];
  __shared__ float Ew[64];
  int blk = blockIdx.x; int chunk = NXC/128; int c0b = blk*chunk;
  int tid = threadIdx.x, ta = tid>>4, tb = tid&15, a0 = ta*4, b0 = tb*4;
  float accp[4][4]={{0}}, accm[4][4]={{0}};
  for (int t0=0;t0<chunk;t0+=64){
    int c0 = c0b+t0;
    for (int i=tid;i<64*64;i+=256){
      int r=i>>6, cc=i&63;
      Xt[r][cc] = X[(size_t)r*pitch + c0+cc];
    }
    if (tid < 64) Ew[tid] = E[c0+tid]*fac;
    __syncthreads();
    for (int jj=0;jj<64;jj++){
      float w0 = Ew[jj];
      float wp = (w0>0.f?w0:0.f)*DXf, wm = (w0<0.f?w0:0.f)*DXf;
      float av[4],bv[4];
      #pragma unroll
      for (int k=0;k<4;k++){ av[k]=Xt[a0+k][jj]; bv[k]=Xt[b0+k][jj]; }
      #pragma unroll
      for (int ka=0;ka<4;ka++){
        #pragma unroll
        for (int kb=0;kb<4;kb++){
          float p = av[ka]*bv[kb];
          accp[ka][kb] += p*wp;
          accm[ka][kb] += p*wm;
        }
      }
    }
    __syncthreads();
  }
  float* pb = part + (size_t)blk*PS_E;
  #pragma unroll
  for (int ka=0;ka<4;ka++){
    #pragma unroll
    for (int kb=0;kb<4;kb++){
      int idx = (a0+ka)*64 + (b0+kb);
      pb[idx] = accp[ka][kb];
      pb[4096+idx] = accm[ka][kb];
    }
  }
}

// ---------------- reductions ----------------
__global__ __launch_bounds__(256) void k_reduce32(const float* __restrict__ part, int nb, int ps,
                                                  float* __restrict__ dst, int n){
  int i = blockIdx.x*256 + threadIdx.x;
  if (i < n){
    float s = 0.f;
    for (int b=0;b<nb;b++) s += part[(size_t)b*ps + i];
    dst[i] = s;
  }
}
__global__ __launch_bounds__(256) void k_reduce64(const double* __restrict__ part, int nb, int ps,
                                                  double* __restrict__ dst, int n){
  int i = blockIdx.x*256 + threadIdx.x;
  if (i < n){
    double s = 0.0;
    for (int b=0;b<nb;b++) s += part[(size_t)b*ps + i];
    dst[i] = s;
  }
}

// ---------------- prep1: Vl/Vr, avec, flux_out1 ----------------
__global__ __launch_bounds__(256) void k_prep1(
  const float* __restrict__ Ve, const float* __restrict__ Vi,
  const float* __restrict__ Se, const float* __restrict__ Si, const float* __restrict__ Xi,
  const float* __restrict__ VDe, const float* __restrict__ VDi,
  float* __restrict__ Vle, float* __restrict__ Vre, float* __restrict__ Vli, float* __restrict__ Vri,
  float* __restrict__ ae, float* __restrict__ ai, float* __restrict__ fluxg)
{
  int t = threadIdx.x;
  const float* g0e = VDe; const float* g1e = VDe+4096;
  const float* g0i = VDi; const float* g1i = VDi+4096;
  const float* sVe = VDe+16384; const float* sVi = VDi+16384;
  const float* wvi = VDi+16512;
  for (int i=t;i<4096;i+=256){
    int a=i>>6, b=i&63;
    float v0a=Ve[(size_t)a*NVC], v0b=Ve[(size_t)b*NVC];
    float vea=Ve[(size_t)a*NVC+NVC-1], veb=Ve[(size_t)b*NVC+NVC-1];
    Vle[i] = (g0e[i] - v0a*v0b) - g1e[i];
    Vre[i] = g1e[b*64+a] - g0e[i] + vea*veb;
    float w0a=Vi[(size_t)a*NVC], w0b=Vi[(size_t)b*NVC];
    float wea=Vi[(size_t)a*NVC+NVC-1], web=Vi[(size_t)b*NVC+NVC-1];
    Vli[i] = (g0i[i] - w0a*w0b) - g1i[i];
    Vri[i] = g1i[b*64+a] - g0i[i] + wea*web;
  }
  __shared__ float red[64];
  if (t < 64){
    float s1=0.f,s2=0.f,tr=0.f;
    for (int q=0;q<64;q++){
      s1 += Se[t*64+q]*sVe[q];
      s2 += Si[t*64+q]*sVi[q];
      tr += Xi[(size_t)q*NXC + (NXC-1)]*Si[q*64+t];
    }
    ae[t]=s1; ai[t]=s2; red[t]=tr*wvi[t];
  }
  __syncthreads();
  if (t==0){ float s=0.f; for (int r=0;r<64;r++) s+=red[r]; fluxg[0]=s; }
}

// ---------------- prep2: avec (post-K S), flux_out2 ----------------
__global__ __launch_bounds__(256) void k_prep2(const float* __restrict__ Sce, const float* __restrict__ Sci,
    const float* __restrict__ VDe, const float* __restrict__ VDi, const float* __restrict__ XiN,
    float* __restrict__ ae, float* __restrict__ ai, float* __restrict__ fluxg)
{
  const float* sVe = VDe+16384; const float* sVi = VDi+16384; const float* wvi = VDi+16512;
  __shared__ float red[64];
  int t=threadIdx.x;
  if (t<64){
    float s1=0.f,s2=0.f,tr=0.f;
    for (int q=0;q<64;q++){
      s1 += Sce[t*64+q]*sVe[q];
      s2 += Sci[t*64+q]*sVi[q];
      tr += XiN[(size_t)q*OUTWC + (NXC-1)]*Sci[q*64+t];
    }
    ae[t]=s1; ai[t]=s2; red[t]=tr*wvi[t];
  }
  __syncthreads();
  if (t==0){ float s=0.f; for(int r=0;r<64;r++) s+=red[r]; fluxg[1]=s; }
}

// ---------------- prep3: avec (post-S S), flux_out3, Xng ----------------
__global__ __launch_bounds__(256) void k_prep3(const float* __restrict__ S2e, const float* __restrict__ S2i,
    const float* __restrict__ VDe, const float* __restrict__ VDi, const float* __restrict__ XiN,
    const float* __restrict__ XDe, const float* __restrict__ XDi,
    float* __restrict__ ae, float* __restrict__ ai,
    float* __restrict__ Xnge, float* __restrict__ Xngi, float* __restrict__ fluxg)
{
  const float* sVe = VDe+16384; const float* sVi = VDi+16384; const float* wvi = VDi+16512;
  const float* Ge = XDe; const float* Gi = XDi;
  const float* XGe = XDe+8192; const float* XGi = XDi+8192;
  __shared__ float red[64];
  int t=threadIdx.x;
  if (t<64){
    float s1=0.f,s2=0.f,tr=0.f;
    for (int q=0;q<64;q++){
      s1 += S2e[t*64+q]*sVe[q];
      s2 += S2i[t*64+q]*sVi[q];
      tr += XiN[(size_t)q*OUTWC + (NXC-1)]*S2i[q*64+t];
    }
    ae[t]=s1; ai[t]=s2; red[t]=tr*wvi[t];
  }
  __syncthreads();
  if (t==0){ float s=0.f; for(int r=0;r<64;r++) s+=red[r]; fluxg[2]=s; }
  __syncthreads();
  if (t<64){
    float y1=0.f,y2=0.f;
    for (int q=0;q<64;q++){ y1 += Ge[t*64+q]*ae[q]; y2 += Gi[t*64+q]*ai[q]; }
    float f3 = fluxg[2];
    Xnge[t] = 1.0f *DXf*DVf*y1 + f3*XGe[t];
    Xngi[t] = 0.04f*DXf*DVf*y2 + f3*XGi[t];
  }
}

// ---------------- rho ----------------
__global__ __launch_bounds__(256) void k_rho(const float* __restrict__ Xe, int pe,
                                             const float* __restrict__ Xi, int pi,
                                             const float* __restrict__ ae, const float* __restrict__ ai,
                                             float* __restrict__ rho){
  int x = blockIdx.x*256 + threadIdx.x;
  float s = 0.f;
  for (int r=0;r<64;r++) s += ai[r]*Xi[(size_t)r*pi + x] - ae[r]*Xe[(size_t)r*pe + x];
  rho[x] = DVf*s;
}

// ---------------- poisson: E = cumsum(rho)*DX - mean ----------------
__global__ __launch_bounds__(1024) void k_poisson(const float* __restrict__ rho, float* __restrict__ E){
  __shared__ float wsum[16];
  __shared__ float bsum[16];
  int t = threadIdx.x;
  int base = t*32;
  float loc[32];
  float run = 0.f;
  #pragma unroll
  for (int i=0;i<32;i++){ run += rho[base+i]; loc[i]=run; }
  float v = run;
  for (int off=1; off<64; off<<=1){
    float u = __shfl_up(v, off, 64);
    if ((t&63) >= off) v += u;
  }
  int wave = t>>6;
  if ((t&63)==63) wsum[wave] = v;
  __syncthreads();
  if (t==0){
    float a=0.f;
    for (int w0=0;w0<16;w0++){ float x=wsum[w0]; wsum[w0]=a; a+=x; }
  }
  __syncthreads();
  float offset = wsum[wave] + (v - run);
  float msum = 0.f;
  #pragma unroll
  for (int i=0;i<32;i++){ float e = DXf*(offset + loc[i]); loc[i]=e; msum += e; }
  float rs = msum;
  for (int off=32; off>0; off>>=1) rs += __shfl_down(rs, off, 64);
  if ((t&63)==0) bsum[wave]=rs;
  __syncthreads();
  if (t==0){ float a=0.f; for(int w0=0;w0<16;w0++) a+=bsum[w0]; bsum[0]=a; }
  __syncthreads();
  float mean = bsum[0]/(float)NXC;
  #pragma unroll
  for (int i=0;i<32;i++) E[base+i] = loc[i]-mean;
}

// ---------------- K step ----------------
__global__ __launch_bounds__(256) void k_kstep(const float* __restrict__ X, const float* __restrict__ S,
    const float* __restrict__ E, const float* __restrict__ gsh, const float* __restrict__ VD,
    const float* __restrict__ Vl, const float* __restrict__ Vr, const float* __restrict__ fluxg,
    float nu, float fac, float* __restrict__ Kout)
{
  __shared__ float Xt[64][66];
  __shared__ float Kt[64][66];
  const float* vpm = VD + 8192;
  const float* vmm = VD + 12288;
  const float* sV  = VD + 16384;
  const float* VMv = VD + 16448;
  int x0 = blockIdx.x*64;
  int tid = threadIdx.x;
  for (int i=tid;i<64*66;i+=256){
    int r = i/66, cc = i%66;
    int x = x0 - 1 + cc;
    Xt[r][cc] = (x>=0 && x<NXC)? X[(size_t)r*NXC + x] : 0.f;
  }
  __syncthreads();
  for (int i=tid;i<64*66;i+=256){
    int q = i/66, cc = i%66;
    float a = 0.f;
    for (int p=0;p<64;p++) a += S[p*64+q]*Xt[p][cc];
    Kt[q][cc] = a;
  }
  __syncthreads();
  float fo = fluxg[0];
  const float DTDX = DTf/DXf;
  for (int i=tid;i<4096;i+=256){
    int r = i>>6, xl = i&63;
    int cc = xl+1, x = x0+xl;
    float Ex = fac*E[x];
    float ep = Ex>0.f?Ex:0.f, em = Ex<0.f?Ex:0.f;
    float acc=0.f, nacc=0.f;
    for (int q=0;q<64;q++){
      float k0=Kt[q][cc], km=Kt[q][cc-1], kp=Kt[q][cc+1];
      float vp_=vpm[r*64+q], vm_=vmm[r*64+q];
      float c0 = -DTDX*(vp_ - vm_) - DTf*(ep*Vl[r*64+q] + em*Vr[r*64+q]);
      acc += c0*k0 + DTDX*(vp_*km - vm_*kp);
      nacc += sV[q]*k0;
    }
    float y = Kt[r][cc]*(1.f - DTf*nu) + acc + DTf*(nacc*DVf*nu + fo*gsh[x])*VMv[r];
    Kout[(size_t)r*NXC + x] = y;
  }
}

// ---------------- L step ----------------
__global__ __launch_bounds__(256) void k_lstep(const float* __restrict__ V, const float* __restrict__ S2,
    const float* __restrict__ ED, const float* __restrict__ XD, const float* __restrict__ Xng,
    float nu, float Amax, float* __restrict__ Lout)
{
  __shared__ float Vt[64][66];
  __shared__ float Lt[64][66];
  const float* Ep = ED; const float* Em = ED+4096;
  const float* G = XD; const float* H = XD+4096;
  int v0 = blockIdx.x*64;
  int tid = threadIdx.x;
  for (int i=tid;i<64*66;i+=256){
    int r=i/66, cc=i%66; int vv=v0-1+cc;
    Vt[r][cc] = (vv>=0 && vv<NVC)? V[(size_t)r*NVC + vv] : 0.f;
  }
  __syncthreads();
  for (int i=tid;i<64*66;i+=256){
    int r=i/66, cc=i%66;
    float a=0.f;
    for (int q=0;q<64;q++) a += S2[r*64+q]*Vt[q][cc];
    Lt[r][cc]=a;
  }
  __syncthreads();
  const float DTDV = DTf/DVf;
  float fm = sqrtf(Amax*INV2PI);
  for (int i=tid;i<4096;i+=256){
    int r=i>>6, vl=i&63;
    int cc=vl+1, vgl=v0+vl;
    float vs = -VMAXf + (vgl+0.5f)*DVf;
    float vp = vs>0.f?vs:0.f, vm = vs<0.f?vs:0.f;
    float acc=0.f;
    for (int q=0;q<64;q++){
      float l0=Lt[q][cc], lm=Lt[q][cc-1], lp=Lt[q][cc+1];
      float g=G[r*64+q], h=H[r*64+q], ht=H[q*64+r];
      float ep=Ep[r*64+q], em=Em[r*64+q];
      float c0 = -DTf*(vp*(g-h) + vm*(ht-g) + nu*DXf*g) - DTDV*(ep-em);
      acc += c0*l0 + DTDV*(ep*lm - em*lp);
    }
    float mv = fm*expf(-0.5f*Amax*vs*vs);
    float y = Lt[r][cc] + acc + DTf*Xng[r]*mv;
    Lout[(size_t)r*NVC + vgl] = y;
  }
}

// ---------------- S step ----------------
struct SArgs {
  const float *S, *XD, *ED, *VD, *Vl, *Vr, *avec;
  float *S2;
  float nu;
};
__global__ __launch_bounds__(256) void k_sstep(SArgs ea, SArgs ia, const float* __restrict__ fluxg){
  SArgs A = (blockIdx.x==0)? ea : ia;
  const float* G = A.XD; const float* H = A.XD+4096; const float* XG = A.XD+8192;
  const float* Ep = A.ED; const float* Em = A.ED+4096;
  const float* vpm = A.VD+8192; const float* vmm = A.VD+12288; const float* VMv = A.VD+16448;
  __shared__ float Sl[64*65];
  __shared__ float Tt[64*65];
  __shared__ float ACC[64*65];
  __shared__ float xng[64];
  int tid = threadIdx.x;
  for (int i=tid;i<4096;i+=256) Sl[(i>>6)*65+(i&63)] = A.S[i];
  __syncthreads();
  // Tt = (G - H) @ S
  for (int i=tid;i<4096;i+=256){
    int a=i>>6,b=i&63; float s=0.f;
    for (int c=0;c<64;c++) s += (G[a*64+c]-H[a*64+c])*Sl[c*65+b];
    Tt[a*65+b]=s;
  }
  __syncthreads();
  // ACC = Tt @ vpm
  for (int i=tid;i<4096;i+=256){
    int a=i>>6,b=i&63; float s=0.f;
    for (int c=0;c<64;c++) s += Tt[a*65+c]*vpm[c*64+b];
    ACC[a*65+b]=s;
  }
  __syncthreads();
  // Tt = (H^T - G) @ S
  for (int i=tid;i<4096;i+=256){
    int a=i>>6,b=i&63; float s=0.f;
    for (int c=0;c<64;c++) s += (H[c*64+a]-G[a*64+c])*Sl[c*65+b];
    Tt[a*65+b]=s;
  }
  __syncthreads();
  // ACC += Tt @ vmm
  for (int i=tid;i<4096;i+=256){
    int a=i>>6,b=i&63; float s=0.f;
    for (int c=0;c<64;c++) s += Tt[a*65+c]*vmm[c*64+b];
    ACC[a*65+b]+=s;
  }
  __syncthreads();
  // Tt = Ep @ S
  for (int i=tid;i<4096;i+=256){
    int a=i>>6,b=i&63; float s=0.f;
    for (int c=0;c<64;c++) s += Ep[a*64+c]*Sl[c*65+b];
    Tt[a*65+b]=s;
  }
  __syncthreads();
  // ACC += Tt @ Vl^T
  for (int i=tid;i<4096;i+=256){
    int a=i>>6,b=i&63; float s=0.f;
    for (int c=0;c<64;c++) s += Tt[a*65+c]*A.Vl[b*64+c];
    ACC[a*65+b]+=s;
  }
  __syncthreads();
  // Tt = Em @ S
  for (int i=tid;i<4096;i+=256){
    int a=i>>6,b=i&63; float s=0.f;
    for (int c=0;c<64;c++) s += Em[a*64+c]*Sl[c*65+b];
    Tt[a*65+b]=s;
  }
  __syncthreads();
  // ACC += Tt @ Vr^T
  for (int i=tid;i<4096;i+=256){
    int a=i>>6,b=i&63; float s=0.f;
    for (int c=0;c<64;c++) s += Tt[a*65+c]*A.Vr[b*64+c];
    ACC[a*65+b]+=s;
  }
  // xng
  if (tid<64){
    float y=0.f;
    for (int q=0;q<64;q++) y += G[tid*64+q]*A.avec[q];
    xng[tid] = A.nu*DXf*DVf*y + fluxg[1]*XG[tid];
  }
  __syncthreads();
  // S2 = S + DT*(ACC + nu*DX*(G@S) - xng*VM^T)
  for (int i=tid;i<4096;i+=256){
    int a=i>>6,b=i&63; float s=0.f;
    for (int c=0;c<64;c++) s += G[a*64+c]*Sl[c*65+b];
    float accv = ACC[a*65+b] + A.nu*DXf*s - xng[a]*VMv[b];
    A.S2[i] = A.S[i] + DTf*accv;
  }
}

// ---------------- Gram (fp64 partials) ----------------
__global__ __launch_bounds__(256) void k_gram(const float* __restrict__ A, int n, double* __restrict__ part){
  __shared__ float At[64][65];
  int blk = blockIdx.x, nb = gridDim.x;
  int chunk = n/nb;
  int c0b = blk*chunk;
  int tid=threadIdx.x, ta=tid>>4, tb=tid&15, a0=ta*4, b0=tb*4;
  double acc[4][4];
  #pragma unroll
  for (int ka=0;ka<4;ka++){
    #pragma unroll
    for (int kb=0;kb<4;kb++) acc[ka][kb]=0.0;
  }
  for (int t0=0;t0<chunk;t0+=64){
    int c0=c0b+t0;
    for (int i=tid;i<64*64;i+=256){ int r=i>>6, cc=i&63; At[r][cc]=A[(size_t)r*n + c0+cc]; }
    __syncthreads();
    for (int cc=0;cc<64;cc++){
      float av[4],bv[4];
      #pragma unroll
      for(int k=0;k<4;k++){ av[k]=At[a0+k][cc]; bv[k]=At[b0+k][cc]; }
      #pragma unroll
      for(int ka=0;ka<4;ka++){
        #pragma unroll
        for(int kb=0;kb<4;kb++) acc[ka][kb] += (double)av[ka]*(double)bv[kb];
      }
    }
    __syncthreads();
  }
  double* pb = part + (size_t)blk*4096;
  #pragma unroll
  for(int ka=0;ka<4;ka++){
    #pragma unroll
    for(int kb=0;kb<4;kb++) pb[(a0+ka)*64 + b0+kb] = acc[ka][kb];
  }
}

// ---------------- small QR: chol + inverse + bottom-chol ----------------
__device__ inline void chol_upper65(double* M, int tid){
  for (int k=0;k<64;k++){
    if (tid==0){ double d = M[k*65+k]; M[k*65+k] = sqrt(d > 0.0 ? d : 1e-300); }
    __syncthreads();
    if (tid>k && tid<64) M[k*65+tid] /= M[k*65+k];
    __syncthreads();
    if (tid>k && tid<64){
      int c=tid; double lkc = M[k*65+c];
      for (int r2=k+1;r2<=c;r2++) M[r2*65+c] -= M[k*65+r2]*lkc;
    }
    __syncthreads();
  }
}

__global__ __launch_bounds__(256) void k_qr1(const double* __restrict__ Gd, const float* __restrict__ A, int n,
                                             double* __restrict__ Rc, float* __restrict__ Lwg, float* __restrict__ Cg)
{
  __shared__ double Lg[64*65];
  __shared__ float Lw[64*65];
  int tid = threadIdx.x;
  for (int i=tid;i<4096;i+=256){ Lg[(i>>6)*65 + (i&63)] = Gd[i]; }
  __syncthreads();
  chol_upper65(Lg, tid);                 // Lg upper = R, G = R^T R
  for (int i=tid;i<4096;i+=256){ int r=i>>6,c=i&63; Rc[i] = (c>=r)? Lg[r*65+c] : 0.0; }
  // invert R -> Lw (upper)
  if (tid<64){
    int c=tid;
    Lw[c*65+c] = (float)(1.0/Lg[c*65+c]);
    for (int r2=c-1;r2>=0;r2--){
      double s=0.0;
      for (int j=r2+1;j<=c;j++) s += Lg[r2*65+j]*(double)Lw[j*65+c];
      Lw[r2*65+c] = (float)(-s/Lg[r2*65+r2]);
    }
    for (int r2=c+1;r2<64;r2++) Lw[r2*65+c] = 0.f;
  }
  __syncthreads();
  for (int i=tid;i<4096;i+=256){ Lwg[i] = Lw[(i>>6)*65+(i&63)]; }
  __syncthreads();
  // Atop into Lw
  for (int i=tid;i<4096;i+=256){ int c=i>>6, x=i&63; Lw[c*65+x] = A[(size_t)c*n + x]; }
  __syncthreads();
  // Gbot = G - Atop^T Atop into Lg
  for (int i=tid;i<4096;i+=256){
    int r=i>>6, c=i&63;
    double s = Gd[i];
    for (int x=0;x<64;x++) s -= (double)Lw[r*65+x]*(double)Lw[c*65+x];
    Lg[r*65+c] = s;
  }
  __syncthreads();
  chol_upper65(Lg, tid);                 // C upper, Gbot = C^T C
  for (int i=tid;i<4096;i+=256){ int r=i>>6,c=i&63; Cg[i] = (c>=r)? (float)Lg[r*65+c] : 0.f; }
}

// ---------------- small QR: compressed Householder -> signs, outputs ----------------
__global__ __launch_bounds__(256) void k_qr2(const float* __restrict__ A, int n,
    const float* __restrict__ Cg, const double* __restrict__ Rc, const float* __restrict__ Lwg,
    float scaleS, float invQ, float* __restrict__ SolveM,
    float* __restrict__ SoutK, float* __restrict__ SoutL, int outPitch, int mode)
{
  __shared__ float AH[64*129];   // col-major: column c at AH[c*129 + i], i<128
  __shared__ float Dv[64];
  __shared__ float bc0[1];
  int tid=threadIdx.x;
  for (int i=tid;i<4096;i+=256){ int c=i>>6, x=i&63; AH[c*129 + x] = A[(size_t)c*n + x]; }
  for (int i=tid;i<4096;i+=256){ int r=i>>6, c=i&63; AH[c*129 + 64 + r] = Cg[r*64+c]; }
  __syncthreads();
  for (int k=0;k<64;k++){
    if (tid==k){
      float sg=0.f;
      for (int i2=k;i2<128;i2++){ float v=AH[k*129+i2]; sg += v*v; }
      float al = AH[k*129+k];
      float beta = (al >= 0.f)? -sqrtf(sg) : sqrtf(sg);
      Dv[k] = (beta >= 0.f)? 1.f : -1.f;
      bc0[0] = sg - al*beta;
      AH[k*129+k] = al - beta;
    }
    __syncthreads();
    float vv = bc0[0];
    if (tid>k && tid<64 && vv > 0.f){
      int c=tid;
      float s=0.f;
      for (int i2=k;i2<128;i2++) s += AH[k*129+i2]*AH[c*129+i2];
      float f = s/vv;
      for (int i2=k;i2<128;i2++) AH[c*129+i2] -= f*AH[k*129+i2];
    }
    __syncthreads();
  }
  for (int i=tid;i<4096;i+=256){
    int r=i>>6, q=i&63;
    SolveM[i] = (q<=r)? (Dv[r]*Lwg[q*64+r]*invQ) : 0.f;
    if (mode==0){
      SoutK[i] = (q>=r)? (float)((double)Dv[r]*Rc[r*64+q]*(double)scaleS) : 0.f;
    } else {
      SoutL[(size_t)r*outPitch + q] = (r>=q)? (float)((double)Dv[q]*Rc[q*64+r]*(double)scaleS) : 0.f;
    }
  }
}

// ---------------- Q formation: Out = SolveM @ A ----------------
__global__ __launch_bounds__(256) void k_qform(const float* __restrict__ A, int n,
    const float* __restrict__ M, float* __restrict__ Out, int pitch)
{
  int x = blockIdx.x*256 + threadIdx.x;
  int r0 = blockIdx.y*16;
  float acc[16];
  #pragma unroll
  for (int rr=0;rr<16;rr++) acc[rr]=0.f;
  for (int q=0;q<64;q++){
    float aq = A[(size_t)q*n + x];
    #pragma unroll
    for (int rr=0;rr<16;rr++) acc[rr] += M[(r0+rr)*64 + q]*aq;
  }
  #pragma unroll
  for (int rr=0;rr<16;rr++) Out[(size_t)(r0+rr)*pitch + x] = acc[rr];
}

// ======================= host =======================
extern "C" void kernel_launch(void* const* d_in, const int* in_sizes, int n_in,
                              void* d_out, int out_size, void* d_ws, size_t ws_size,
                              hipStream_t stream)
{
  (void)in_sizes; (void)n_in; (void)out_size; (void)ws_size;
  const float* Xe = (const float*)d_in[0];
  const float* Se = (const float*)d_in[1];
  const float* Ve = (const float*)d_in[2];
  const float* Xi = (const float*)d_in[3];
  const float* Si = (const float*)d_in[4];
  const float* Vi = (const float*)d_in[5];
  float* out = (float*)d_out;
  float* w = (float*)d_ws;

  size_t o = 0;
  auto alloc = [&](size_t nn){ size_t r=o; o += (nn+63)&~(size_t)63; return r; };
  size_t F_VD_E = alloc(PS_V);
  size_t F_VD_I = alloc(PS_V);
  size_t F_XD_E = alloc(PS_X);
  size_t F_XD_I = alloc(PS_X);
  size_t F_ED_E = alloc(PS_E);
  size_t F_ED_I = alloc(PS_E);
  size_t F_VL_E = alloc(4096), F_VR_E = alloc(4096), F_VL_I = alloc(4096), F_VR_I = alloc(4096);
  size_t F_SC_E = alloc(4096), F_SC_I = alloc(4096), F_S2_E = alloc(4096), F_S2_I = alloc(4096);
  size_t F_SOLVE = alloc(4096);
  size_t F_LWG = alloc(4096);
  size_t F_CG  = alloc(4096);
  size_t F_AE = alloc(64), F_AI = alloc(64), F_XNGE = alloc(64), F_XNGI = alloc(64);
  size_t F_FLUX = alloc(64);
  size_t F_GSH = alloc(NXC);
  size_t F_RHO = alloc(NXC);
  size_t F_E   = alloc(NXC);
  size_t F_KE = alloc((size_t)64*NXC);
  size_t F_KI = alloc((size_t)64*NXC);
  size_t F_LE = F_KE;   // reuse: Ke dead after its qform
  size_t F_LI = F_KI;
  size_t F_PART = alloc(1060864);
  size_t F_GQR = alloc(8192);  // 4096 doubles
  size_t F_RC  = alloc(8192);
  double* Gqr = (double*)(w + F_GQR);
  double* Rc  = (double*)(w + F_RC);
  double* partd = (double*)(w + F_PART);
  float* part = w + F_PART;

  float sqDX = sqrtf(DXf), isqDX = 1.f/sqrtf(DXf);
  float sqDV = sqrtf(DVf), isqDV = 1.f/sqrtf(DVf);
  const float NUE = 1.0f, NUI = 0.04f;
  const float FACE = -1.0f, FACI = 1.0f/1836.0f;

  // --- V-derived stats ---
  k_vstats<<<64,256,0,stream>>>(Ve, part, 1.0f);
  k_reduce32<<<(PS_V+255)/256,256,0,stream>>>(part, 64, PS_V, w+F_VD_E, PS_V);
  k_vstats<<<64,256,0,stream>>>(Vi, part, 1836.0f);
  k_reduce32<<<(PS_V+255)/256,256,0,stream>>>(part, 64, PS_V, w+F_VD_I, PS_V);
  k_gshape<<<1,1024,0,stream>>>(w+F_GSH);
  k_prep1<<<1,256,0,stream>>>(Ve, Vi, Se, Si, Xi, w+F_VD_E, w+F_VD_I,
                              w+F_VL_E, w+F_VR_E, w+F_VL_I, w+F_VR_I,
                              w+F_AE, w+F_AI, w+F_FLUX);
  // --- K step ---
  k_rho<<<NXC/256,256,0,stream>>>(Xe, NXC, Xi, NXC, w+F_AE, w+F_AI, w+F_RHO);
  k_poisson<<<1,1024,0,stream>>>(w+F_RHO, w+F_E);
  k_kstep<<<NXC/64,256,0,stream>>>(Xe, Se, w+F_E, w+F_GSH, w+F_VD_E, w+F_VL_E, w+F_VR_E, w+F_FLUX, NUE, FACE, w+F_KE);
  k_kstep<<<NXC/64,256,0,stream>>>(Xi, Si, w+F_E, w+F_GSH, w+F_VD_I, w+F_VL_I, w+F_VR_I, w+F_FLUX, NUI, FACI, w+F_KI);
  // --- QR of Ke^T ---
  k_gram<<<128,256,0,stream>>>(w+F_KE, NXC, partd);
  k_reduce64<<<16,256,0,stream>>>(partd, 128, 4096, Gqr, 4096);
  k_qr1<<<1,256,0,stream>>>(Gqr, w+F_KE, NXC, Rc, w+F_LWG, w+F_CG);
  k_qr2<<<1,256,0,stream>>>(w+F_KE, NXC, w+F_CG, Rc, w+F_LWG, sqDX, isqDX, w+F_SOLVE, w+F_SC_E, out, OUTWC, 0);
  k_qform<<<dim3(NXC/256,4),256,0,stream>>>(w+F_KE, NXC, w+F_SOLVE, out, OUTWC);
  // --- QR of Ki^T ---
  k_gram<<<128,256,0,stream>>>(w+F_KI, NXC, partd);
  k_reduce64<<<16,256,0,stream>>>(partd, 128, 4096, Gqr, 4096);
  k_qr1<<<1,256,0,stream>>>(Gqr, w+F_KI, NXC, Rc, w+F_LWG, w+F_CG);
  k_qr2<<<1,256,0,stream>>>(w+F_KI, NXC, w+F_CG, Rc, w+F_LWG, sqDX, isqDX, w+F_SOLVE, w+F_SC_I, out, OUTWC, 0);
  k_qform<<<dim3(NXC/256,4),256,0,stream>>>(w+F_KI, NXC, w+F_SOLVE, out + (size_t)64*OUTWC, OUTWC);
  // --- X stats on new X ---
  k_xstats<<<128,256,0,stream>>>(out, OUTWC, w+F_GSH, part);
  k_reduce32<<<(PS_X+255)/256,256,0,stream>>>(part, 128, PS_X, w+F_XD_E, PS_X);
  k_xstats<<<128,256,0,stream>>>(out + (size_t)64*OUTWC, OUTWC, w+F_GSH, part);
  k_reduce32<<<(PS_X+255)/256,256,0,stream>>>(part, 128, PS_X, w+F_XD_I, PS_X);
  // --- S step ---
  k_prep2<<<1,256,0,stream>>>(w+F_SC_E, w+F_SC_I, w+F_VD_E, w+F_VD_I, out + (size_t)64*OUTWC,
                              w+F_AE, w+F_AI, w+F_FLUX);
  k_rho<<<NXC/256,256,0,stream>>>(out, OUTWC, out + (size_t)64*OUTWC, OUTWC, w+F_AE, w+F_AI, w+F_RHO);
  k_poisson<<<1,1024,0,stream>>>(w+F_RHO, w+F_E);
  k_eweight<<<128,256,0,stream>>>(out, OUTWC, w+F_E, FACE, part);
  k_reduce32<<<(PS_E+255)/256,256,0,stream>>>(part, 128, PS_E, w+F_ED_E, PS_E);
  k_eweight<<<128,256,0,stream>>>(out + (size_t)64*OUTWC, OUTWC, w+F_E, FACI, part);
  k_reduce32<<<(PS_E+255)/256,256,0,stream>>>(part, 128, PS_E, w+F_ED_I, PS_E);
  SArgs ea; ea.S=w+F_SC_E; ea.XD=w+F_XD_E; ea.ED=w+F_ED_E; ea.VD=w+F_VD_E; ea.Vl=w+F_VL_E; ea.Vr=w+F_VR_E; ea.avec=w+F_AE; ea.S2=w+F_S2_E; ea.nu=NUE;
  SArgs ia; ia.S=w+F_SC_I; ia.XD=w+F_XD_I; ia.ED=w+F_ED_I; ia.VD=w+F_VD_I; ia.Vl=w+F_VL_I; ia.Vr=w+F_VR_I; ia.avec=w+F_AI; ia.S2=w+F_S2_I; ia.nu=NUI;
  k_sstep<<<2,256,0,stream>>>(ea, ia, w+F_FLUX);
  // --- L step ---
  k_prep3<<<1,256,0,stream>>>(w+F_S2_E, w+F_S2_I, w+F_VD_E, w+F_VD_I, out + (size_t)64*OUTWC,
                              w+F_XD_E, w+F_XD_I, w+F_AE, w+F_AI, w+F_XNGE, w+F_XNGI, w+F_FLUX);
  k_rho<<<NXC/256,256,0,stream>>>(out, OUTWC, out + (size_t)64*OUTWC, OUTWC, w+F_AE, w+F_AI, w+F_RHO);
  k_poisson<<<1,1024,0,stream>>>(w+F_RHO, w+F_E);
  k_eweight<<<128,256,0,stream>>>(out, OUTWC, w+F_E, FACE, part);
  k_reduce32<<<(PS_E+255)/256,256,0,stream>>>(part, 128, PS_E, w+F_ED_E, PS_E);
  k_eweight<<<128,256,0,stream>>>(out + (size_t)64*OUTWC, OUTWC, w+F_E, FACI, part);
  k_reduce32<<<(PS_E+255)/256,256,0,stream>>>(part, 128, PS_E, w+F_ED_I, PS_E);
  k_lstep<<<NVC/64,256,0,stream>>>(Ve, w+F_S2_E, w+F_ED_E, w+F_XD_E, w+F_XNGE, NUE, 1.0f,    w+F_LE);
  k_lstep<<<NVC/64,256,0,stream>>>(Vi, w+F_S2_I, w+F_ED_I, w+F_XD_I, w+F_XNGI, NUI, 1836.0f, w+F_LI);
  // --- QR of Le^T ---
  k_gram<<<64,256,0,stream>>>(w+F_LE, NVC, partd);
  k_reduce64<<<16,256,0,stream>>>(partd, 64, 4096, Gqr, 4096);
  k_qr1<<<1,256,0,stream>>>(Gqr, w+F_LE, NVC, Rc, w+F_LWG, w+F_CG);
  k_qr2<<<1,256,0,stream>>>(w+F_LE, NVC, w+F_CG, Rc, w+F_LWG, sqDV, isqDV, w+F_SOLVE, w+F_SC_E, out + NXC, OUTWC, 1);
  k_qform<<<dim3(NVC/256,4),256,0,stream>>>(w+F_LE, NVC, w+F_SOLVE, out + NXC + 64, OUTWC);
  // --- QR of Li^T ---
  k_gram<<<64,256,0,stream>>>(w+F_LI, NVC, partd);
  k_reduce64<<<16,256,0,stream>>>(partd, 64, 4096, Gqr, 4096);
  k_qr1<<<1,256,0,stream>>>(Gqr, w+F_LI, NVC, Rc, w+F_LWG, w+F_CG);
  k_qr2<<<1,256,0,stream>>>(w+F_LI, NVC, w+F_CG, Rc, w+F_LWG, sqDV, isqDV, w+F_SOLVE, w+F_SC_I, out + (size_t)64*OUTWC + NXC, OUTWC, 1);
  k_qform<<<dim3(NVC/256,4),256,0,stream>>>(w+F_LI, NVC, w+F_SOLVE, out + (size_t)64*OUTWC + NXC + 64, OUTWC);
}

// Round 2
// 3294.311 us; speedup vs baseline: 1.5158x; 1.5158x over previous
//
#include <hip/hip_runtime.h>
#include <math.h>

#define NXC 32768
#define NVC 16384
#define OUTWC (NXC + 64 + NVC)

static constexpr float DXf   = 1.0f/32768.0f;
static constexpr float DVf   = 16.0f/16384.0f;
static constexpr float DTf   = 1e-3f;
static constexpr float VMAXf = 8.0f;
static constexpr float INV2PI= 0.15915494309189535f;

#define PS_V 16576
#define PS_X 8256
#define PS_E 8192

// ---------------- gshape ----------------
__global__ __launch_bounds__(1024) void k_gshape(float* __restrict__ g){
  __shared__ float red[1024];
  int t = threadIdx.x;
  float s = 0.f;
  for (int i = t; i < NXC; i += 1024){
    float x = (i + 0.5f)*DXf - 0.5f;
    float xx = x*10.0f;
    float gv = expf(-0.5f*xx*xx);
    g[i] = gv; s += gv;
  }
  red[t] = s; __syncthreads();
  for (int o = 512; o > 0; o >>= 1){ if (t < o) red[t] += red[t+o]; __syncthreads(); }
  float norm = 1.0f/(red[0]*DXf);
  for (int i = t; i < NXC; i += 1024) g[i] *= norm;
}

// ---------------- V stats ----------------
__global__ __launch_bounds__(256) void k_vstats(const float* __restrict__ V, float* __restrict__ part, float Amax){
  __shared__ float Vt[64][66];
  int blk = blockIdx.x;
  int chunk = NVC/64;
  int c0b = blk*chunk;
  int tid = threadIdx.x;
  int ta = tid >> 4, tb = tid & 15;
  int a0 = ta*4, b0 = tb*4;
  float acc0[4][4]={{0}}, acc1[4][4]={{0}}, accp[4][4]={{0}}, accm[4][4]={{0}};
  float vsv[4]={0,0,0,0}, vvm[4]={0,0,0,0}, vwv[4]={0,0,0,0};
  float fm = sqrtf(Amax*INV2PI);
  for (int t0 = 0; t0 < chunk; t0 += 64){
    int c0 = c0b + t0;
    for (int i = tid; i < 64*65; i += 256){
      int r = i/65, cc = i%65;
      int c = c0 - 1 + cc;
      Vt[r][cc] = (c >= 0 && c < NVC) ? V[(size_t)r*NVC + c] : 0.f;
    }
    __syncthreads();
    for (int jj = 0; jj < 64; ++jj){
      int j = c0 + jj;
      float vs = -VMAXf + (j + 0.5f)*DVf;
      float wpj = (vs > 0.f ? vs : 0.f)*DVf;
      float wmj = (vs < 0.f ? vs : 0.f)*DVf;
      float av[4], bv[4], bm[4];
      #pragma unroll
      for (int k=0;k<4;k++){ av[k]=Vt[a0+k][jj+1]; bv[k]=Vt[b0+k][jj+1]; bm[k]=Vt[b0+k][jj]; }
      float lag = (j >= 1) ? 1.f : 0.f;
      #pragma unroll
      for (int ka=0;ka<4;ka++){
        #pragma unroll
        for (int kb=0;kb<4;kb++){
          float p = av[ka]*bv[kb];
          acc0[ka][kb] += p;
          accp[ka][kb] += p*wpj;
          accm[ka][kb] += p*wmj;
          acc1[ka][kb] += lag*av[ka]*bm[kb];
        }
      }
      if (tb == 0){
        float mv = fm*expf(-0.5f*Amax*vs*vs)*DVf;
        #pragma unroll
        for (int k=0;k<4;k++){
          vsv[k] += av[k];
          vvm[k] += av[k]*mv;
          vwv[k] += av[k]*wpj;
        }
      }
    }
    __syncthreads();
  }
  float* pb = part + (size_t)blk*PS_V;
  #pragma unroll
  for (int ka=0;ka<4;ka++){
    #pragma unroll
    for (int kb=0;kb<4;kb++){
      int idx = (a0+ka)*64 + (b0+kb);
      pb[idx]        = acc0[ka][kb];
      pb[4096+idx]   = acc1[ka][kb];
      pb[8192+idx]   = accp[ka][kb];
      pb[12288+idx]  = accm[ka][kb];
    }
  }
  if (tb == 0){
    #pragma unroll
    for (int k=0;k<4;k++){
      pb[16384 + a0+k] = vsv[k];
      pb[16448 + a0+k] = vvm[k];
      pb[16512 + a0+k] = vwv[k];
    }
  }
}

// ---------------- X stats ----------------
__global__ __launch_bounds__(256) void k_xstats(const float* __restrict__ X, int pitch,
                                                const float* __restrict__ gsh, float* __restrict__ part){
  __shared__ float Xt[64][66];
  int blk = blockIdx.x;
  int chunk = NXC/128;
  int c0b = blk*chunk;
  int tid = threadIdx.x, ta = tid>>4, tb = tid&15, a0 = ta*4, b0 = tb*4;
  float accg[4][4]={{0}}, acch[4][4]={{0}};
  float axg[4]={0,0,0,0};
  for (int t0=0;t0<chunk;t0+=64){
    int c0 = c0b+t0;
    for (int i=tid;i<64*65;i+=256){
      int r=i/65, cc=i%65; int x=c0-1+cc;
      Xt[r][cc] = (x>=0 && x<NXC) ? X[(size_t)r*pitch + x] : 0.f;
    }
    __syncthreads();
    for (int jj=0;jj<64;jj++){
      int x = c0+jj;
      float av[4],bv[4],bm[4];
      #pragma unroll
      for (int k=0;k<4;k++){ av[k]=Xt[a0+k][jj+1]; bv[k]=Xt[b0+k][jj+1]; bm[k]=Xt[b0+k][jj]; }
      float lag = (x>=1)?1.f:0.f;
      #pragma unroll
      for (int ka=0;ka<4;ka++){
        #pragma unroll
        for (int kb=0;kb<4;kb++){
          accg[ka][kb] += av[ka]*bv[kb];
          acch[ka][kb] += lag*av[ka]*bm[kb];
        }
      }
      if (tb==0){
        float gw = gsh[x]*DXf;
        #pragma unroll
        for (int k=0;k<4;k++) axg[k] += av[k]*gw;
      }
    }
    __syncthreads();
  }
  float* pb = part + (size_t)blk*PS_X;
  #pragma unroll
  for (int ka=0;ka<4;ka++){
    #pragma unroll
    for (int kb=0;kb<4;kb++){
      int idx = (a0+ka)*64 + (b0+kb);
      pb[idx] = accg[ka][kb];
      pb[4096+idx] = acch[ka][kb];
    }
  }
  if (tb==0){
    #pragma unroll
    for (int k=0;k<4;k++) pb[8192 + a0+k] = axg[k];
  }
}

// ---------------- E-weighted grams ----------------
__global__ __launch_bounds__(256) void k_eweight(const float* __restrict__ X, int pitch,
                                                 const float* __restrict__ E, float fac, float* __restrict__ part){
  __shared__ float Xt[64][65];
  __shared__ float Ew[64];
  int blk = blockIdx.x; int chunk = NXC/128; int c0b = blk*chunk;
  int tid = threadIdx.x, ta = tid>>4, tb = tid&15, a0 = ta*4, b0 = tb*4;
  float accp[4][4]={{0}}, accm[4][4]={{0}};
  for (int t0=0;t0<chunk;t0+=64){
    int c0 = c0b+t0;
    for (int i=tid;i<64*64;i+=256){
      int r=i>>6, cc=i&63;
      Xt[r][cc] = X[(size_t)r*pitch + c0+cc];
    }
    if (tid < 64) Ew[tid] = E[c0+tid]*fac;
    __syncthreads();
    for (int jj=0;jj<64;jj++){
      float w0 = Ew[jj];
      float wp = (w0>0.f?w0:0.f)*DXf, wm = (w0<0.f?w0:0.f)*DXf;
      float av[4],bv[4];
      #pragma unroll
      for (int k=0;k<4;k++){ av[k]=Xt[a0+k][jj]; bv[k]=Xt[b0+k][jj]; }
      #pragma unroll
      for (int ka=0;ka<4;ka++){
        #pragma unroll
        for (int kb=0;kb<4;kb++){
          float p = av[ka]*bv[kb];
          accp[ka][kb] += p*wp;
          accm[ka][kb] += p*wm;
        }
      }
    }
    __syncthreads();
  }
  float* pb = part + (size_t)blk*PS_E;
  #pragma unroll
  for (int ka=0;ka<4;ka++){
    #pragma unroll
    for (int kb=0;kb<4;kb++){
      int idx = (a0+ka)*64 + (b0+kb);
      pb[idx] = accp[ka][kb];
      pb[4096+idx] = accm[ka][kb];
    }
  }
}

// ---------------- reductions ----------------
__global__ __launch_bounds__(256) void k_reduce32(const float* __restrict__ part, int nb, int ps,
                                                  float* __restrict__ dst, int n){
  int i = blockIdx.x*256 + threadIdx.x;
  if (i < n){
    float s = 0.f;
    for (int b=0;b<nb;b++) s += part[(size_t)b*ps + i];
    dst[i] = s;
  }
}
__global__ __launch_bounds__(256) void k_reduce64(const double* __restrict__ part, int nb, int ps,
                                                  double* __restrict__ dst, int n){
  int i = blockIdx.x*256 + threadIdx.x;
  if (i < n){
    double s = 0.0;
    for (int b=0;b<nb;b++) s += part[(size_t)b*ps + i];
    dst[i] = s;
  }
}

// ---------------- prep kernels ----------------
__global__ __launch_bounds__(256) void k_prep1(
  const float* __restrict__ Ve, const float* __restrict__ Vi,
  const float* __restrict__ Se, const float* __restrict__ Si, const float* __restrict__ Xi,
  const float* __restrict__ VDe, const float* __restrict__ VDi,
  float* __restrict__ Vle, float* __restrict__ Vre, float* __restrict__ Vli, float* __restrict__ Vri,
  float* __restrict__ ae, float* __restrict__ ai, float* __restrict__ fluxg)
{
  int t = threadIdx.x;
  const float* g0e = VDe; const float* g1e = VDe+4096;
  const float* g0i = VDi; const float* g1i = VDi+4096;
  const float* sVe = VDe+16384; const float* sVi = VDi+16384;
  const float* wvi = VDi+16512;
  for (int i=t;i<4096;i+=256){
    int a=i>>6, b=i&63;
    float v0a=Ve[(size_t)a*NVC], v0b=Ve[(size_t)b*NVC];
    float vea=Ve[(size_t)a*NVC+NVC-1], veb=Ve[(size_t)b*NVC+NVC-1];
    Vle[i] = (g0e[i] - v0a*v0b) - g1e[i];
    Vre[i] = g1e[b*64+a] - g0e[i] + vea*veb;
    float w0a=Vi[(size_t)a*NVC], w0b=Vi[(size_t)b*NVC];
    float wea=Vi[(size_t)a*NVC+NVC-1], web=Vi[(size_t)b*NVC+NVC-1];
    Vli[i] = (g0i[i] - w0a*w0b) - g1i[i];
    Vri[i] = g1i[b*64+a] - g0i[i] + wea*web;
  }
  __shared__ float red[64];
  if (t < 64){
    float s1=0.f,s2=0.f,tr=0.f;
    for (int q=0;q<64;q++){
      s1 += Se[t*64+q]*sVe[q];
      s2 += Si[t*64+q]*sVi[q];
      tr += Xi[(size_t)q*NXC + (NXC-1)]*Si[q*64+t];
    }
    ae[t]=s1; ai[t]=s2; red[t]=tr*wvi[t];
  }
  __syncthreads();
  if (t==0){ float s=0.f; for (int r=0;r<64;r++) s+=red[r]; fluxg[0]=s; }
}

__global__ __launch_bounds__(256) void k_prep2(const float* __restrict__ Sce, const float* __restrict__ Sci,
    const float* __restrict__ VDe, const float* __restrict__ VDi, const float* __restrict__ XiN,
    float* __restrict__ ae, float* __restrict__ ai, float* __restrict__ fluxg)
{
  const float* sVe = VDe+16384; const float* sVi = VDi+16384; const float* wvi = VDi+16512;
  __shared__ float red[64];
  int t=threadIdx.x;
  if (t<64){
    float s1=0.f,s2=0.f,tr=0.f;
    for (int q=0;q<64;q++){
      s1 += Sce[t*64+q]*sVe[q];
      s2 += Sci[t*64+q]*sVi[q];
      tr += XiN[(size_t)q*OUTWC + (NXC-1)]*Sci[q*64+t];
    }
    ae[t]=s1; ai[t]=s2; red[t]=tr*wvi[t];
  }
  __syncthreads();
  if (t==0){ float s=0.f; for(int r=0;r<64;r++) s+=red[r]; fluxg[1]=s; }
}

__global__ __launch_bounds__(256) void k_prep3(const float* __restrict__ S2e, const float* __restrict__ S2i,
    const float* __restrict__ VDe, const float* __restrict__ VDi, const float* __restrict__ XiN,
    const float* __restrict__ XDe, const float* __restrict__ XDi,
    float* __restrict__ ae, float* __restrict__ ai,
    float* __restrict__ Xnge, float* __restrict__ Xngi, float* __restrict__ fluxg)
{
  const float* sVe = VDe+16384; const float* sVi = VDi+16384; const float* wvi = VDi+16512;
  const float* Ge = XDe; const float* Gi = XDi;
  const float* XGe = XDe+8192; const float* XGi = XDi+8192;
  __shared__ float red[64];
  int t=threadIdx.x;
  if (t<64){
    float s1=0.f,s2=0.f,tr=0.f;
    for (int q=0;q<64;q++){
      s1 += S2e[t*64+q]*sVe[q];
      s2 += S2i[t*64+q]*sVi[q];
      tr += XiN[(size_t)q*OUTWC + (NXC-1)]*S2i[q*64+t];
    }
    ae[t]=s1; ai[t]=s2; red[t]=tr*wvi[t];
  }
  __syncthreads();
  if (t==0){ float s=0.f; for(int r=0;r<64;r++) s+=red[r]; fluxg[2]=s; }
  __syncthreads();
  if (t<64){
    float y1=0.f,y2=0.f;
    for (int q=0;q<64;q++){ y1 += Ge[t*64+q]*ae[q]; y2 += Gi[t*64+q]*ai[q]; }
    float f3 = fluxg[2];
    Xnge[t] = 1.0f *DXf*DVf*y1 + f3*XGe[t];
    Xngi[t] = 0.04f*DXf*DVf*y2 + f3*XGi[t];
  }
}

// ---------------- rho ----------------
__global__ __launch_bounds__(256) void k_rho(const float* __restrict__ Xe, int pe,
                                             const float* __restrict__ Xi, int pi,
                                             const float* __restrict__ ae, const float* __restrict__ ai,
                                             float* __restrict__ rho){
  int x = blockIdx.x*256 + threadIdx.x;
  float s = 0.f;
  for (int r=0;r<64;r++) s += ai[r]*Xi[(size_t)r*pi + x] - ae[r]*Xe[(size_t)r*pe + x];
  rho[x] = DVf*s;
}

// ---------------- poisson ----------------
__global__ __launch_bounds__(1024) void k_poisson(const float* __restrict__ rho, float* __restrict__ E){
  __shared__ float wsum[16];
  __shared__ float bsum[16];
  int t = threadIdx.x;
  int base = t*32;
  float loc[32];
  float run = 0.f;
  #pragma unroll
  for (int i=0;i<32;i++){ run += rho[base+i]; loc[i]=run; }
  float v = run;
  for (int off=1; off<64; off<<=1){
    float u = __shfl_up(v, off, 64);
    if ((t&63) >= off) v += u;
  }
  int wave = t>>6;
  if ((t&63)==63) wsum[wave] = v;
  __syncthreads();
  if (t==0){
    float a=0.f;
    for (int w0=0;w0<16;w0++){ float x=wsum[w0]; wsum[w0]=a; a+=x; }
  }
  __syncthreads();
  float offset = wsum[wave] + (v - run);
  float msum = 0.f;
  #pragma unroll
  for (int i=0;i<32;i++){ float e = DXf*(offset + loc[i]); loc[i]=e; msum += e; }
  float rs = msum;
  for (int off=32; off>0; off>>=1) rs += __shfl_down(rs, off, 64);
  if ((t&63)==0) bsum[wave]=rs;
  __syncthreads();
  if (t==0){ float a=0.f; for(int w0=0;w0<16;w0++) a+=bsum[w0]; bsum[0]=a; }
  __syncthreads();
  float mean = bsum[0]/(float)NXC;
  #pragma unroll
  for (int i=0;i<32;i++) E[base+i] = loc[i]-mean;
}

// ---------------- K step ----------------
__global__ __launch_bounds__(256) void k_kstep(const float* __restrict__ X, const float* __restrict__ S,
    const float* __restrict__ E, const float* __restrict__ gsh, const float* __restrict__ VD,
    const float* __restrict__ Vl, const float* __restrict__ Vr, const float* __restrict__ fluxg,
    float nu, float fac, float* __restrict__ Kout)
{
  __shared__ float Xt[64][66];
  __shared__ float Kt[64][66];
  const float* vpm = VD + 8192;
  const float* vmm = VD + 12288;
  const float* sV  = VD + 16384;
  const float* VMv = VD + 16448;
  int x0 = blockIdx.x*64;
  int tid = threadIdx.x;
  for (int i=tid;i<64*66;i+=256){
    int r = i/66, cc = i%66;
    int x = x0 - 1 + cc;
    Xt[r][cc] = (x>=0 && x<NXC)? X[(size_t)r*NXC + x] : 0.f;
  }
  __syncthreads();
  for (int i=tid;i<64*66;i+=256){
    int q = i/66, cc = i%66;
    float a = 0.f;
    for (int p=0;p<64;p++) a += S[p*64+q]*Xt[p][cc];
    Kt[q][cc] = a;
  }
  __syncthreads();
  float fo = fluxg[0];
  const float DTDX = DTf/DXf;
  for (int i=tid;i<4096;i+=256){
    int r = i>>6, xl = i&63;
    int cc = xl+1, x = x0+xl;
    float Ex = fac*E[x];
    float ep = Ex>0.f?Ex:0.f, em = Ex<0.f?Ex:0.f;
    float acc=0.f, nacc=0.f;
    for (int q=0;q<64;q++){
      float k0=Kt[q][cc], km=Kt[q][cc-1], kp=Kt[q][cc+1];
      float vp_=vpm[r*64+q], vm_=vmm[r*64+q];
      float c0 = -DTDX*(vp_ - vm_) - DTf*(ep*Vl[r*64+q] + em*Vr[r*64+q]);
      acc += c0*k0 + DTDX*(vp_*km - vm_*kp);
      nacc += sV[q]*k0;
    }
    float y = Kt[r][cc]*(1.f - DTf*nu) + acc + DTf*(nacc*DVf*nu + fo*gsh[x])*VMv[r];
    Kout[(size_t)r*NXC + x] = y;
  }
}

// ---------------- L step ----------------
__global__ __launch_bounds__(256) void k_lstep(const float* __restrict__ V, const float* __restrict__ S2,
    const float* __restrict__ ED, const float* __restrict__ XD, const float* __restrict__ Xng,
    float nu, float Amax, float* __restrict__ Lout)
{
  __shared__ float Vt[64][66];
  __shared__ float Lt[64][66];
  const float* Ep = ED; const float* Em = ED+4096;
  const float* G = XD; const float* H = XD+4096;
  int v0 = blockIdx.x*64;
  int tid = threadIdx.x;
  for (int i=tid;i<64*66;i+=256){
    int r=i/66, cc=i%66; int vv=v0-1+cc;
    Vt[r][cc] = (vv>=0 && vv<NVC)? V[(size_t)r*NVC + vv] : 0.f;
  }
  __syncthreads();
  for (int i=tid;i<64*66;i+=256){
    int r=i/66, cc=i%66;
    float a=0.f;
    for (int q=0;q<64;q++) a += S2[r*64+q]*Vt[q][cc];
    Lt[r][cc]=a;
  }
  __syncthreads();
  const float DTDV = DTf/DVf;
  float fm = sqrtf(Amax*INV2PI);
  for (int i=tid;i<4096;i+=256){
    int r=i>>6, vl=i&63;
    int cc=vl+1, vgl=v0+vl;
    float vs = -VMAXf + (vgl+0.5f)*DVf;
    float vp = vs>0.f?vs:0.f, vm = vs<0.f?vs:0.f;
    float acc=0.f;
    for (int q=0;q<64;q++){
      float l0=Lt[q][cc], lm=Lt[q][cc-1], lp=Lt[q][cc+1];
      float g=G[r*64+q], h=H[r*64+q], ht=H[q*64+r];
      float ep=Ep[r*64+q], em=Em[r*64+q];
      float c0 = -DTf*(vp*(g-h) + vm*(ht-g) + nu*DXf*g) - DTDV*(ep-em);
      acc += c0*l0 + DTDV*(ep*lm - em*lp);
    }
    float mv = fm*expf(-0.5f*Amax*vs*vs);
    float y = Lt[r][cc] + acc + DTf*Xng[r]*mv;
    Lout[(size_t)r*NVC + vgl] = y;
  }
}

// ---------------- S step ----------------
struct SArgs {
  const float *S, *XD, *ED, *VD, *Vl, *Vr, *avec;
  float *S2;
  float nu;
};
__global__ __launch_bounds__(256) void k_sstep(SArgs ea, SArgs ia, const float* __restrict__ fluxg){
  SArgs A = (blockIdx.x==0)? ea : ia;
  const float* G = A.XD; const float* H = A.XD+4096; const float* XG = A.XD+8192;
  const float* Ep = A.ED; const float* Em = A.ED+4096;
  const float* vpm = A.VD+8192; const float* vmm = A.VD+12288; const float* VMv = A.VD+16448;
  __shared__ float Sl[64*65];
  __shared__ float Tt[64*65];
  __shared__ float ACC[64*65];
  __shared__ float xng[64];
  int tid = threadIdx.x;
  for (int i=tid;i<4096;i+=256) Sl[(i>>6)*65+(i&63)] = A.S[i];
  __syncthreads();
  for (int i=tid;i<4096;i+=256){
    int a=i>>6,b=i&63; float s=0.f;
    for (int c=0;c<64;c++) s += (G[a*64+c]-H[a*64+c])*Sl[c*65+b];
    Tt[a*65+b]=s;
  }
  __syncthreads();
  for (int i=tid;i<4096;i+=256){
    int a=i>>6,b=i&63; float s=0.f;
    for (int c=0;c<64;c++) s += Tt[a*65+c]*vpm[c*64+b];
    ACC[a*65+b]=s;
  }
  __syncthreads();
  for (int i=tid;i<4096;i+=256){
    int a=i>>6,b=i&63; float s=0.f;
    for (int c=0;c<64;c++) s += (H[c*64+a]-G[a*64+c])*Sl[c*65+b];
    Tt[a*65+b]=s;
  }
  __syncthreads();
  for (int i=tid;i<4096;i+=256){
    int a=i>>6,b=i&63; float s=0.f;
    for (int c=0;c<64;c++) s += Tt[a*65+c]*vmm[c*64+b];
    ACC[a*65+b]+=s;
  }
  __syncthreads();
  for (int i=tid;i<4096;i+=256){
    int a=i>>6,b=i&63; float s=0.f;
    for (int c=0;c<64;c++) s += Ep[a*64+c]*Sl[c*65+b];
    Tt[a*65+b]=s;
  }
  __syncthreads();
  for (int i=tid;i<4096;i+=256){
    int a=i>>6,b=i&63; float s=0.f;
    for (int c=0;c<64;c++) s += Tt[a*65+c]*A.Vl[b*64+c];
    ACC[a*65+b]+=s;
  }
  __syncthreads();
  for (int i=tid;i<4096;i+=256){
    int a=i>>6,b=i&63; float s=0.f;
    for (int c=0;c<64;c++) s += Em[a*64+c]*Sl[c*65+b];
    Tt[a*65+b]=s;
  }
  __syncthreads();
  for (int i=tid;i<4096;i+=256){
    int a=i>>6,b=i&63; float s=0.f;
    for (int c=0;c<64;c++) s += Tt[a*65+c]*A.Vr[b*64+c];
    ACC[a*65+b]+=s;
  }
  if (tid<64){
    float y=0.f;
    for (int q=0;q<64;q++) y += G[tid*64+q]*A.avec[q];
    xng[tid] = A.nu*DXf*DVf*y + fluxg[1]*XG[tid];
  }
  __syncthreads();
  for (int i=tid;i<4096;i+=256){
    int a=i>>6,b=i&63; float s=0.f;
    for (int c=0;c<64;c++) s += G[a*64+c]*Sl[c*65+b];
    float accv = ACC[a*65+b] + A.nu*DXf*s - xng[a]*VMv[b];
    A.S2[i] = A.S[i] + DTf*accv;
  }
}

// ---------------- Gram (fp64 partials) ----------------
__global__ __launch_bounds__(256) void k_gram(const float* __restrict__ A, int n, double* __restrict__ part){
  __shared__ float At[64][65];
  int blk = blockIdx.x, nb = gridDim.x;
  int chunk = n/nb;
  int c0b = blk*chunk;
  int tid=threadIdx.x, ta=tid>>4, tb=tid&15, a0=ta*4, b0=tb*4;
  double acc[4][4];
  #pragma unroll
  for (int ka=0;ka<4;ka++){
    #pragma unroll
    for (int kb=0;kb<4;kb++) acc[ka][kb]=0.0;
  }
  for (int t0=0;t0<chunk;t0+=64){
    int c0=c0b+t0;
    for (int i=tid;i<64*64;i+=256){ int r=i>>6, cc=i&63; At[r][cc]=A[(size_t)r*n + c0+cc]; }
    __syncthreads();
    for (int cc=0;cc<64;cc++){
      float av[4],bv[4];
      #pragma unroll
      for(int k=0;k<4;k++){ av[k]=At[a0+k][cc]; bv[k]=At[b0+k][cc]; }
      #pragma unroll
      for(int ka=0;ka<4;ka++){
        #pragma unroll
        for(int kb=0;kb<4;kb++) acc[ka][kb] += (double)av[ka]*(double)bv[kb];
      }
    }
    __syncthreads();
  }
  double* pb = part + (size_t)blk*4096;
  #pragma unroll
  for(int ka=0;ka<4;ka++){
    #pragma unroll
    for(int kb=0;kb<4;kb++) pb[(a0+ka)*64 + b0+kb] = acc[ka][kb];
  }
}

// ---------------- parallel Cholesky (upper, 64x64, stride-65 double) ----------------
__device__ inline void chol_par(double* M, int tid){
  for (int k=0;k<64;k++){
    if (tid<64){
      double v = M[k*65+tid];
      double pv = __shfl(v, k, 64);
      double dk = sqrt(pv > 0.0 ? pv : 1e-300);
      if (tid==k) M[k*65+k] = dk;
      else if (tid>k) M[k*65+tid] = v/dk;
    }
    __syncthreads();
    for (int i=(k+1)*64 + tid; i<4096; i+=256){
      int r=i>>6, c=i&63;
      if (c>=r) M[r*65+c] -= M[k*65+r]*M[k*65+c];
    }
    __syncthreads();
  }
}

// ---------------- qr1: chol + blocked inverse + bottom-chol ----------------
__global__ __launch_bounds__(256) void k_qr1(const double* __restrict__ Gd, const float* __restrict__ A, int n,
                                             double* __restrict__ Rc, float* __restrict__ Lwg, float* __restrict__ Cg)
{
  __shared__ double Lg[64*65];
  __shared__ double Td[32*33];
  __shared__ float Lw[64*65];
  int tid = threadIdx.x;
  for (int i=tid;i<4096;i+=256){ Lg[(i>>6)*65 + (i&63)] = Gd[i]; }
  __syncthreads();
  chol_par(Lg, tid);                     // Lg upper = R, G = R^T R
  for (int i=tid;i<4096;i+=256){ int r=i>>6,c=i&63; Rc[i] = (c>=r)? Lg[r*65+c] : 0.0; }
  __syncthreads();
  // blocked inverse of R -> Lw (upper, float, double accumulation)
  // Phase A: diagonal 32x32 blocks, per-column back-substitution
  if (tid<64){
    int c=tid, b0=c&~31;
    Lw[c*65+c] = (float)(1.0/Lg[c*65+c]);
    for (int r=c-1;r>=b0;r--){
      double s=0.0;
      for (int j=r+1;j<=c;j++) s += Lg[r*65+j]*(double)Lw[j*65+c];
      Lw[r*65+c] = (float)(-s/Lg[r*65+r]);
    }
    for (int r=c+1;r<b0+32;r++) Lw[r*65+c]=0.f;
    if (b0==0){ for (int r=32;r<64;r++) Lw[r*65+c]=0.f; }
  }
  __syncthreads();
  // Phase B: T = R12 @ W22
  for (int i=tid;i<1024;i+=256){
    int r=i>>5, c=32+(i&31);
    double s=0.0;
    for (int j=32;j<64;j++) s += Lg[r*65+j]*(double)Lw[j*65+c];
    Td[(i>>5)*33+(i&31)] = s;
  }
  __syncthreads();
  // W12 = -W11 @ T
  for (int i=tid;i<1024;i+=256){
    int r=i>>5, c=i&31;
    double s=0.0;
    for (int j=r;j<32;j++) s += (double)Lw[r*65+j]*Td[j*33+c];
    Lw[r*65+32+c] = (float)(-s);
  }
  __syncthreads();
  for (int i=tid;i<4096;i+=256){ Lwg[i] = Lw[(i>>6)*65+(i&63)]; }
  __syncthreads();
  // Atop into Lw
  for (int i=tid;i<4096;i+=256){ int c=i>>6, x=i&63; Lw[c*65+x] = A[(size_t)c*n + x]; }
  __syncthreads();
  // Gbot = G - Atop^T Atop into Lg
  for (int i=tid;i<4096;i+=256){
    int r=i>>6, c=i&63;
    double s = Gd[i];
    for (int x=0;x<64;x++) s -= (double)Lw[r*65+x]*(double)Lw[c*65+x];
    Lg[r*65+c] = s;
  }
  __syncthreads();
  chol_par(Lg, tid);                     // C upper, Gbot = C^T C
  for (int i=tid;i<4096;i+=256){ int r=i>>6,c=i&63; Cg[i] = (c>=r)? (float)Lg[r*65+c] : 0.f; }
}

// ---------------- qr2: parallel compressed Householder -> signs, outputs ----------------
__global__ __launch_bounds__(256) void k_qr2(const float* __restrict__ A, int n,
    const float* __restrict__ Cg, const double* __restrict__ Rc, const float* __restrict__ Lwg,
    float scaleS, float invQ, float* __restrict__ SolveM,
    float* __restrict__ SoutK, float* __restrict__ SoutL, int outPitch, int mode)
{
  __shared__ float AH[64*130];   // col-major: column c at AH[c*130 + i], i<128
  __shared__ float Dv[64];
  __shared__ float bc0[1];
  int tid=threadIdx.x;
  for (int i=tid;i<4096;i+=256){ int c=i>>6, x=i&63; AH[c*130 + x] = A[(size_t)c*n + x]; }
  for (int i=tid;i<4096;i+=256){ int r=i>>6, c=i&63; AH[c*130 + 64 + r] = Cg[r*64+c]; }
  __syncthreads();
  int col = tid>>2, l4 = tid&3;
  int i0 = l4*32;
  for (int k=0;k<64;k++){
    // pivot: wave 0 computes column-k norm via shuffle reduction
    if (tid < 64){
      float v0 = (tid>=k)? AH[k*130+tid] : 0.f;
      float v1 = AH[k*130+64+tid];
      float sg = v0*v0 + v1*v1;
      #pragma unroll
      for (int o=32;o>0;o>>=1) sg += __shfl_xor(sg, o, 64);
      float al = AH[k*130+k];
      float beta = (al >= 0.f)? -sqrtf(sg) : sqrtf(sg);
      if (tid==0){
        Dv[k] = (beta >= 0.f)? 1.f : -1.f;
        bc0[0] = sg - al*beta;
        AH[k*130+k] = al - beta;
      }
    }
    __syncthreads();
    float vv = bc0[0];
    if (col>k && vv > 0.f){
      int istart = i0 > k ? i0 : k;
      int iend = i0+32;
      float s=0.f;
      for (int i=istart;i<iend;i++) s += AH[k*130+i]*AH[col*130+i];
      s += __shfl_xor(s, 1, 64);
      s += __shfl_xor(s, 2, 64);
      float f = s/vv;
      for (int i=istart;i<iend;i++) AH[col*130+i] -= f*AH[k*130+i];
    }
    __syncthreads();
  }
  for (int i=tid;i<4096;i+=256){
    int r=i>>6, q=i&63;
    SolveM[i] = (q<=r)? (Dv[r]*Lwg[q*64+r]*invQ) : 0.f;
    if (mode==0){
      SoutK[i] = (q>=r)? (float)((double)Dv[r]*Rc[r*64+q]*(double)scaleS) : 0.f;
    } else {
      SoutL[(size_t)r*outPitch + q] = (r>=q)? (float)((double)Dv[q]*Rc[q*64+r]*(double)scaleS) : 0.f;
    }
  }
}

// ---------------- Q formation ----------------
__global__ __launch_bounds__(256) void k_qform(const float* __restrict__ A, int n,
    const float* __restrict__ M, float* __restrict__ Out, int pitch)
{
  int x = blockIdx.x*256 + threadIdx.x;
  int r0 = blockIdx.y*16;
  float acc[16];
  #pragma unroll
  for (int rr=0;rr<16;rr++) acc[rr]=0.f;
  for (int q=0;q<64;q++){
    float aq = A[(size_t)q*n + x];
    #pragma unroll
    for (int rr=0;rr<16;rr++) acc[rr] += M[(r0+rr)*64 + q]*aq;
  }
  #pragma unroll
  for (int rr=0;rr<16;rr++) Out[(size_t)(r0+rr)*pitch + x] = acc[rr];
}

// ======================= host =======================
extern "C" void kernel_launch(void* const* d_in, const int* in_sizes, int n_in,
                              void* d_out, int out_size, void* d_ws, size_t ws_size,
                              hipStream_t stream)
{
  (void)in_sizes; (void)n_in; (void)out_size; (void)ws_size;
  const float* Xe = (const float*)d_in[0];
  const float* Se = (const float*)d_in[1];
  const float* Ve = (const float*)d_in[2];
  const float* Xi = (const float*)d_in[3];
  const float* Si = (const float*)d_in[4];
  const float* Vi = (const float*)d_in[5];
  float* out = (float*)d_out;
  float* w = (float*)d_ws;

  size_t o = 0;
  auto alloc = [&](size_t nn){ size_t r=o; o += (nn+63)&~(size_t)63; return r; };
  size_t F_VD_E = alloc(PS_V);
  size_t F_VD_I = alloc(PS_V);
  size_t F_XD_E = alloc(PS_X);
  size_t F_XD_I = alloc(PS_X);
  size_t F_ED_E = alloc(PS_E);
  size_t F_ED_I = alloc(PS_E);
  size_t F_VL_E = alloc(4096), F_VR_E = alloc(4096), F_VL_I = alloc(4096), F_VR_I = alloc(4096);
  size_t F_SC_E = alloc(4096), F_SC_I = alloc(4096), F_S2_E = alloc(4096), F_S2_I = alloc(4096);
  size_t F_SOLVE = alloc(4096);
  size_t F_LWG = alloc(4096);
  size_t F_CG  = alloc(4096);
  size_t F_AE = alloc(64), F_AI = alloc(64), F_XNGE = alloc(64), F_XNGI = alloc(64);
  size_t F_FLUX = alloc(64);
  size_t F_GSH = alloc(NXC);
  size_t F_RHO = alloc(NXC);
  size_t F_E   = alloc(NXC);
  size_t F_KE = alloc((size_t)64*NXC);
  size_t F_KI = alloc((size_t)64*NXC);
  size_t F_LE = F_KE;
  size_t F_LI = F_KI;
  size_t F_PART = alloc(1060864);
  size_t F_GQR = alloc(8192);
  size_t F_RC  = alloc(8192);
  double* Gqr = (double*)(w + F_GQR);
  double* Rc  = (double*)(w + F_RC);
  double* partd = (double*)(w + F_PART);
  float* part = w + F_PART;

  float sqDX = sqrtf(DXf), isqDX = 1.f/sqrtf(DXf);
  float sqDV = sqrtf(DVf), isqDV = 1.f/sqrtf(DVf);
  const float NUE = 1.0f, NUI = 0.04f;
  const float FACE = -1.0f, FACI = 1.0f/1836.0f;

  k_vstats<<<64,256,0,stream>>>(Ve, part, 1.0f);
  k_reduce32<<<(PS_V+255)/256,256,0,stream>>>(part, 64, PS_V, w+F_VD_E, PS_V);
  k_vstats<<<64,256,0,stream>>>(Vi, part, 1836.0f);
  k_reduce32<<<(PS_V+255)/256,256,0,stream>>>(part, 64, PS_V, w+F_VD_I, PS_V);
  k_gshape<<<1,1024,0,stream>>>(w+F_GSH);
  k_prep1<<<1,256,0,stream>>>(Ve, Vi, Se, Si, Xi, w+F_VD_E, w+F_VD_I,
                              w+F_VL_E, w+F_VR_E, w+F_VL_I, w+F_VR_I,
                              w+F_AE, w+F_AI, w+F_FLUX);
  k_rho<<<NXC/256,256,0,stream>>>(Xe, NXC, Xi, NXC, w+F_AE, w+F_AI, w+F_RHO);
  k_poisson<<<1,1024,0,stream>>>(w+F_RHO, w+F_E);
  k_kstep<<<NXC/64,256,0,stream>>>(Xe, Se, w+F_E, w+F_GSH, w+F_VD_E, w+F_VL_E, w+F_VR_E, w+F_FLUX, NUE, FACE, w+F_KE);
  k_kstep<<<NXC/64,256,0,stream>>>(Xi, Si, w+F_E, w+F_GSH, w+F_VD_I, w+F_VL_I, w+F_VR_I, w+F_FLUX, NUI, FACI, w+F_KI);
  k_gram<<<128,256,0,stream>>>(w+F_KE, NXC, partd);
  k_reduce64<<<16,256,0,stream>>>(partd, 128, 4096, Gqr, 4096);
  k_qr1<<<1,256,0,stream>>>(Gqr, w+F_KE, NXC, Rc, w+F_LWG, w+F_CG);
  k_qr2<<<1,256,0,stream>>>(w+F_KE, NXC, w+F_CG, Rc, w+F_LWG, sqDX, isqDX, w+F_SOLVE, w+F_SC_E, out, OUTWC, 0);
  k_qform<<<dim3(NXC/256,4),256,0,stream>>>(w+F_KE, NXC, w+F_SOLVE, out, OUTWC);
  k_gram<<<128,256,0,stream>>>(w+F_KI, NXC, partd);
  k_reduce64<<<16,256,0,stream>>>(partd, 128, 4096, Gqr, 4096);
  k_qr1<<<1,256,0,stream>>>(Gqr, w+F_KI, NXC, Rc, w+F_LWG, w+F_CG);
  k_qr2<<<1,256,0,stream>>>(w+F_KI, NXC, w+F_CG, Rc, w+F_LWG, sqDX, isqDX, w+F_SOLVE, w+F_SC_I, out, OUTWC, 0);
  k_qform<<<dim3(NXC/256,4),256,0,stream>>>(w+F_KI, NXC, w+F_SOLVE, out + (size_t)64*OUTWC, OUTWC);
  k_xstats<<<128,256,0,stream>>>(out, OUTWC, w+F_GSH, part);
  k_reduce32<<<(PS_X+255)/256,256,0,stream>>>(part, 128, PS_X, w+F_XD_E, PS_X);
  k_xstats<<<128,256,0,stream>>>(out + (size_t)64*OUTWC, OUTWC, w+F_GSH, part);
  k_reduce32<<<(PS_X+255)/256,256,0,stream>>>(part, 128, PS_X, w+F_XD_I, PS_X);
  k_prep2<<<1,256,0,stream>>>(w+F_SC_E, w+F_SC_I, w+F_VD_E, w+F_VD_I, out + (size_t)64*OUTWC,
                              w+F_AE, w+F_AI, w+F_FLUX);
  k_rho<<<NXC/256,256,0,stream>>>(out, OUTWC, out + (size_t)64*OUTWC, OUTWC, w+F_AE, w+F_AI, w+F_RHO);
  k_poisson<<<1,1024,0,stream>>>(w+F_RHO, w+F_E);
  k_eweight<<<128,256,0,stream>>>(out, OUTWC, w+F_E, FACE, part);
  k_reduce32<<<(PS_E+255)/256,256,0,stream>>>(part, 128, PS_E, w+F_ED_E, PS_E);
  k_eweight<<<128,256,0,stream>>>(out + (size_t)64*OUTWC, OUTWC, w+F_E, FACI, part);
  k_reduce32<<<(PS_E+255)/256,256,0,stream>>>(part, 128, PS_E, w+F_ED_I, PS_E);
  SArgs ea; ea.S=w+F_SC_E; ea.XD=w+F_XD_E; ea.ED=w+F_ED_E; ea.VD=w+F_VD_E; ea.Vl=w+F_VL_E; ea.Vr=w+F_VR_E; ea.avec=w+F_AE; ea.S2=w+F_S2_E; ea.nu=NUE;
  SArgs ia; ia.S=w+F_SC_I; ia.XD=w+F_XD_I; ia.ED=w+F_ED_I; ia.VD=w+F_VD_I; ia.Vl=w+F_VL_I; ia.Vr=w+F_VR_I; ia.avec=w+F_AI; ia.S2=w+F_S2_I; ia.nu=NUI;
  k_sstep<<<2,256,0,stream>>>(ea, ia, w+F_FLUX);
  k_prep3<<<1,256,0,stream>>>(w+F_S2_E, w+F_S2_I, w+F_VD_E, w+F_VD_I, out + (size_t)64*OUTWC,
                              w+F_XD_E, w+F_XD_I, w+F_AE, w+F_AI, w+F_XNGE, w+F_XNGI, w+F_FLUX);
  k_rho<<<NXC/256,256,0,stream>>>(out, OUTWC, out + (size_t)64*OUTWC, OUTWC, w+F_AE, w+F_AI, w+F_RHO);
  k_poisson<<<1,1024,0,stream>>>(w+F_RHO, w+F_E);
  k_eweight<<<128,256,0,stream>>>(out, OUTWC, w+F_E, FACE, part);
  k_reduce32<<<(PS_E+255)/256,256,0,stream>>>(part, 128, PS_E, w+F_ED_E, PS_E);
  k_eweight<<<128,256,0,stream>>>(out + (size_t)64*OUTWC, OUTWC, w+F_E, FACI, part);
  k_reduce32<<<(PS_E+255)/256,256,0,stream>>>(part, 128, PS_E, w+F_ED_I, PS_E);
  k_lstep<<<NVC/64,256,0,stream>>>(Ve, w+F_S2_E, w+F_ED_E, w+F_XD_E, w+F_XNGE, NUE, 1.0f,    w+F_LE);
  k_lstep<<<NVC/64,256,0,stream>>>(Vi, w+F_S2_I, w+F_ED_I, w+F_XD_I, w+F_XNGI, NUI, 1836.0f, w+F_LI);
  k_gram<<<64,256,0,stream>>>(w+F_LE, NVC, partd);
  k_reduce64<<<16,256,0,stream>>>(partd, 64, 4096, Gqr, 4096);
  k_qr1<<<1,256,0,stream>>>(Gqr, w+F_LE, NVC, Rc, w+F_LWG, w+F_CG);
  k_qr2<<<1,256,0,stream>>>(w+F_LE, NVC, w+F_CG, Rc, w+F_LWG, sqDV, isqDV, w+F_SOLVE, w+F_SC_E, out + NXC, OUTWC, 1);
  k_qform<<<dim3(NVC/256,4),256,0,stream>>>(w+F_LE, NVC, w+F_SOLVE, out + NXC + 64, OUTWC);
  k_gram<<<64,256,0,stream>>>(w+F_LI, NVC, partd);
  k_reduce64<<<16,256,0,stream>>>(partd, 64, 4096, Gqr, 4096);
  k_qr1<<<1,256,0,stream>>>(Gqr, w+F_LI, NVC, Rc, w+F_LWG, w+F_CG);
  k_qr2<<<1,256,0,stream>>>(w+F_LI, NVC, w+F_CG, Rc, w+F_LWG, sqDV, isqDV, w+F_SOLVE, w+F_SC_I, out + (size_t)64*OUTWC + NXC, OUTWC, 1);
  k_qform<<<dim3(NVC/256,4),256,0,stream>>>(w+F_LI, NVC, w+F_SOLVE, out + (size_t)64*OUTWC + NXC + 64, OUTWC);
}

// Round 3
// 1828.300 us; speedup vs baseline: 2.7312x; 1.8018x over previous
//
#include <hip/hip_runtime.h>
#include <math.h>

#define NXC 32768
#define NVC 16384
#define OUTWC (NXC + 64 + NVC)

static constexpr float DXf   = 1.0f/32768.0f;
static constexpr float DVf   = 16.0f/16384.0f;
static constexpr float DTf   = 1e-3f;
static constexpr float VMAXf = 8.0f;
static constexpr float INV2PI= 0.15915494309189535f;

#define PS_V 16576
#define PS_X 8256
#define PS_E 8192

// ---------------- gshape ----------------
__global__ __launch_bounds__(1024) void k_gshape(float* __restrict__ g){
  __shared__ float red[1024];
  int t = threadIdx.x;
  float s = 0.f;
  for (int i = t; i < NXC; i += 1024){
    float x = (i + 0.5f)*DXf - 0.5f;
    float xx = x*10.0f;
    float gv = expf(-0.5f*xx*xx);
    g[i] = gv; s += gv;
  }
  red[t] = s; __syncthreads();
  for (int o = 512; o > 0; o >>= 1){ if (t < o) red[t] += red[t+o]; __syncthreads(); }
  float norm = 1.0f/(red[0]*DXf);
  for (int i = t; i < NXC; i += 1024) g[i] *= norm;
}

// ---------------- V stats (fused species via grid.y) ----------------
__global__ __launch_bounds__(256) void k_vstatsf(const float* __restrict__ V0, const float* __restrict__ V1,
                                                 float* __restrict__ part){
  __shared__ float Vt[64][66];
  int sp = blockIdx.y;
  const float* V = sp ? V1 : V0;
  float Amax = sp ? 1836.0f : 1.0f;
  int blk = blockIdx.x;               // 32 blocks per species
  int chunk = NVC/32;                 // 512
  int c0b = blk*chunk;
  int tid = threadIdx.x;
  int ta = tid >> 4, tb = tid & 15;
  int a0 = ta*4, b0 = tb*4;
  float acc0[4][4]={{0}}, acc1[4][4]={{0}}, accp[4][4]={{0}}, accm[4][4]={{0}};
  float vsv[4]={0,0,0,0}, vvm[4]={0,0,0,0}, vwv[4]={0,0,0,0};
  float fm = sqrtf(Amax*INV2PI);
  for (int t0 = 0; t0 < chunk; t0 += 64){
    int c0 = c0b + t0;
    for (int i = tid; i < 64*65; i += 256){
      int r = i/65, cc = i%65;
      int c = c0 - 1 + cc;
      Vt[r][cc] = (c >= 0 && c < NVC) ? V[(size_t)r*NVC + c] : 0.f;
    }
    __syncthreads();
    for (int jj = 0; jj < 64; ++jj){
      int j = c0 + jj;
      float vs = -VMAXf + (j + 0.5f)*DVf;
      float wpj = (vs > 0.f ? vs : 0.f)*DVf;
      float wmj = (vs < 0.f ? vs : 0.f)*DVf;
      float av[4], bv[4], bm[4];
      #pragma unroll
      for (int k=0;k<4;k++){ av[k]=Vt[a0+k][jj+1]; bv[k]=Vt[b0+k][jj+1]; bm[k]=Vt[b0+k][jj]; }
      float lag = (j >= 1) ? 1.f : 0.f;
      #pragma unroll
      for (int ka=0;ka<4;ka++){
        #pragma unroll
        for (int kb=0;kb<4;kb++){
          float p = av[ka]*bv[kb];
          acc0[ka][kb] += p;
          accp[ka][kb] += p*wpj;
          accm[ka][kb] += p*wmj;
          acc1[ka][kb] += lag*av[ka]*bm[kb];
        }
      }
      if (tb == 0){
        float mv = fm*expf(-0.5f*Amax*vs*vs)*DVf;
        #pragma unroll
        for (int k=0;k<4;k++){
          vsv[k] += av[k];
          vvm[k] += av[k]*mv;
          vwv[k] += av[k]*wpj;
        }
      }
    }
    __syncthreads();
  }
  float* pb = part + (size_t)(sp*32+blk)*PS_V;
  #pragma unroll
  for (int ka=0;ka<4;ka++){
    #pragma unroll
    for (int kb=0;kb<4;kb++){
      int idx = (a0+ka)*64 + (b0+kb);
      pb[idx]        = acc0[ka][kb];
      pb[4096+idx]   = acc1[ka][kb];
      pb[8192+idx]   = accp[ka][kb];
      pb[12288+idx]  = accm[ka][kb];
    }
  }
  if (tb == 0){
    #pragma unroll
    for (int k=0;k<4;k++){
      pb[16384 + a0+k] = vsv[k];
      pb[16448 + a0+k] = vvm[k];
      pb[16512 + a0+k] = vwv[k];
    }
  }
}

// ---------------- X stats (fused) ----------------
__global__ __launch_bounds__(256) void k_xstatsf(const float* __restrict__ X0, const float* __restrict__ X1,
                                                 int pitch, const float* __restrict__ gsh, float* __restrict__ part){
  __shared__ float Xt[64][66];
  int sp = blockIdx.y;
  const float* X = sp ? X1 : X0;
  int blk = blockIdx.x;               // 64 per species
  int chunk = NXC/64;                 // 512
  int c0b = blk*chunk;
  int tid = threadIdx.x, ta = tid>>4, tb = tid&15, a0 = ta*4, b0 = tb*4;
  float accg[4][4]={{0}}, acch[4][4]={{0}};
  float axg[4]={0,0,0,0};
  for (int t0=0;t0<chunk;t0+=64){
    int c0 = c0b+t0;
    for (int i=tid;i<64*65;i+=256){
      int r=i/65, cc=i%65; int x=c0-1+cc;
      Xt[r][cc] = (x>=0 && x<NXC) ? X[(size_t)r*pitch + x] : 0.f;
    }
    __syncthreads();
    for (int jj=0;jj<64;jj++){
      int x = c0+jj;
      float av[4],bv[4],bm[4];
      #pragma unroll
      for (int k=0;k<4;k++){ av[k]=Xt[a0+k][jj+1]; bv[k]=Xt[b0+k][jj+1]; bm[k]=Xt[b0+k][jj]; }
      float lag = (x>=1)?1.f:0.f;
      #pragma unroll
      for (int ka=0;ka<4;ka++){
        #pragma unroll
        for (int kb=0;kb<4;kb++){
          accg[ka][kb] += av[ka]*bv[kb];
          acch[ka][kb] += lag*av[ka]*bm[kb];
        }
      }
      if (tb==0){
        float gw = gsh[x]*DXf;
        #pragma unroll
        for (int k=0;k<4;k++) axg[k] += av[k]*gw;
      }
    }
    __syncthreads();
  }
  float* pb = part + (size_t)(sp*64+blk)*PS_X;
  #pragma unroll
  for (int ka=0;ka<4;ka++){
    #pragma unroll
    for (int kb=0;kb<4;kb++){
      int idx = (a0+ka)*64 + (b0+kb);
      pb[idx] = accg[ka][kb];
      pb[4096+idx] = acch[ka][kb];
    }
  }
  if (tb==0){
    #pragma unroll
    for (int k=0;k<4;k++) pb[8192 + a0+k] = axg[k];
  }
}

// ---------------- E-weighted grams (fused) ----------------
__global__ __launch_bounds__(256) void k_eweightf(const float* __restrict__ X0, const float* __restrict__ X1,
                                                  int pitch, const float* __restrict__ E,
                                                  float fac0, float fac1, float* __restrict__ part){
  __shared__ float Xt[64][65];
  __shared__ float Ew[64];
  int sp = blockIdx.y;
  const float* X = sp ? X1 : X0;
  float fac = sp ? fac1 : fac0;
  int blk = blockIdx.x; int chunk = NXC/64; int c0b = blk*chunk;
  int tid = threadIdx.x, ta = tid>>4, tb = tid&15, a0 = ta*4, b0 = tb*4;
  float accp[4][4]={{0}}, accm[4][4]={{0}};
  for (int t0=0;t0<chunk;t0+=64){
    int c0 = c0b+t0;
    for (int i=tid;i<64*64;i+=256){
      int r=i>>6, cc=i&63;
      Xt[r][cc] = X[(size_t)r*pitch + c0+cc];
    }
    if (tid < 64) Ew[tid] = E[c0+tid]*fac;
    __syncthreads();
    for (int jj=0;jj<64;jj++){
      float w0 = Ew[jj];
      float wp = (w0>0.f?w0:0.f)*DXf, wm = (w0<0.f?w0:0.f)*DXf;
      float av[4],bv[4];
      #pragma unroll
      for (int k=0;k<4;k++){ av[k]=Xt[a0+k][jj]; bv[k]=Xt[b0+k][jj]; }
      #pragma unroll
      for (int ka=0;ka<4;ka++){
        #pragma unroll
        for (int kb=0;kb<4;kb++){
          float p = av[ka]*bv[kb];
          accp[ka][kb] += p*wp;
          accm[ka][kb] += p*wm;
        }
      }
    }
    __syncthreads();
  }
  float* pb = part + (size_t)(sp*64+blk)*PS_E;
  #pragma unroll
  for (int ka=0;ka<4;ka++){
    #pragma unroll
    for (int kb=0;kb<4;kb++){
      int idx = (a0+ka)*64 + (b0+kb);
      pb[idx] = accp[ka][kb];
      pb[4096+idx] = accm[ka][kb];
    }
  }
}

// ---------------- reductions (fused species via grid.y) ----------------
__global__ __launch_bounds__(256) void k_reduce32f(const float* __restrict__ part, int nb, int ps,
                                                   float* __restrict__ dst){
  int sp = blockIdx.y;
  int i = blockIdx.x*256 + threadIdx.x;
  if (i < ps){
    float s = 0.f;
    for (int b=0;b<nb;b++) s += part[(size_t)(sp*nb+b)*ps + i];
    dst[(size_t)sp*ps + i] = s;
  }
}
__global__ __launch_bounds__(256) void k_reduce64f(const double* __restrict__ part, int nb,
                                                   double* __restrict__ dst){
  int sp = blockIdx.y;
  int i = blockIdx.x*256 + threadIdx.x;
  if (i < 4096){
    double s = 0.0;
    for (int b=0;b<nb;b++) s += part[(size_t)(sp*nb+b)*4096 + i];
    dst[(size_t)sp*4096 + i] = s;
  }
}

// ---------------- prep kernels ----------------
__global__ __launch_bounds__(256) void k_prep1(
  const float* __restrict__ Ve, const float* __restrict__ Vi,
  const float* __restrict__ Se, const float* __restrict__ Si, const float* __restrict__ Xi,
  const float* __restrict__ VDe, const float* __restrict__ VDi,
  float* __restrict__ Vle, float* __restrict__ Vre, float* __restrict__ Vli, float* __restrict__ Vri,
  float* __restrict__ ae, float* __restrict__ ai, float* __restrict__ fluxg)
{
  int t = threadIdx.x;
  const float* g0e = VDe; const float* g1e = VDe+4096;
  const float* g0i = VDi; const float* g1i = VDi+4096;
  const float* sVe = VDe+16384; const float* sVi = VDi+16384;
  const float* wvi = VDi+16512;
  for (int i=t;i<4096;i+=256){
    int a=i>>6, b=i&63;
    float v0a=Ve[(size_t)a*NVC], v0b=Ve[(size_t)b*NVC];
    float vea=Ve[(size_t)a*NVC+NVC-1], veb=Ve[(size_t)b*NVC+NVC-1];
    Vle[i] = (g0e[i] - v0a*v0b) - g1e[i];
    Vre[i] = g1e[b*64+a] - g0e[i] + vea*veb;
    float w0a=Vi[(size_t)a*NVC], w0b=Vi[(size_t)b*NVC];
    float wea=Vi[(size_t)a*NVC+NVC-1], web=Vi[(size_t)b*NVC+NVC-1];
    Vli[i] = (g0i[i] - w0a*w0b) - g1i[i];
    Vri[i] = g1i[b*64+a] - g0i[i] + wea*web;
  }
  __shared__ float red[64];
  if (t < 64){
    float s1=0.f,s2=0.f,tr=0.f;
    for (int q=0;q<64;q++){
      s1 += Se[t*64+q]*sVe[q];
      s2 += Si[t*64+q]*sVi[q];
      tr += Xi[(size_t)q*NXC + (NXC-1)]*Si[q*64+t];
    }
    ae[t]=s1; ai[t]=s2; red[t]=tr*wvi[t];
  }
  __syncthreads();
  if (t==0){ float s=0.f; for (int r=0;r<64;r++) s+=red[r]; fluxg[0]=s; }
}

__global__ __launch_bounds__(256) void k_prep2(const float* __restrict__ Sce, const float* __restrict__ Sci,
    const float* __restrict__ VDe, const float* __restrict__ VDi, const float* __restrict__ XiN,
    float* __restrict__ ae, float* __restrict__ ai, float* __restrict__ fluxg)
{
  const float* sVe = VDe+16384; const float* sVi = VDi+16384; const float* wvi = VDi+16512;
  __shared__ float red[64];
  int t=threadIdx.x;
  if (t<64){
    float s1=0.f,s2=0.f,tr=0.f;
    for (int q=0;q<64;q++){
      s1 += Sce[t*64+q]*sVe[q];
      s2 += Sci[t*64+q]*sVi[q];
      tr += XiN[(size_t)q*OUTWC + (NXC-1)]*Sci[q*64+t];
    }
    ae[t]=s1; ai[t]=s2; red[t]=tr*wvi[t];
  }
  __syncthreads();
  if (t==0){ float s=0.f; for(int r=0;r<64;r++) s+=red[r]; fluxg[1]=s; }
}

__global__ __launch_bounds__(256) void k_prep3(const float* __restrict__ S2e, const float* __restrict__ S2i,
    const float* __restrict__ VDe, const float* __restrict__ VDi, const float* __restrict__ XiN,
    const float* __restrict__ XDe, const float* __restrict__ XDi,
    float* __restrict__ ae, float* __restrict__ ai,
    float* __restrict__ Xnge, float* __restrict__ Xngi, float* __restrict__ fluxg)
{
  const float* sVe = VDe+16384; const float* sVi = VDi+16384; const float* wvi = VDi+16512;
  const float* Ge = XDe; const float* Gi = XDi;
  const float* XGe = XDe+8192; const float* XGi = XDi+8192;
  __shared__ float red[64];
  int t=threadIdx.x;
  if (t<64){
    float s1=0.f,s2=0.f,tr=0.f;
    for (int q=0;q<64;q++){
      s1 += S2e[t*64+q]*sVe[q];
      s2 += S2i[t*64+q]*sVi[q];
      tr += XiN[(size_t)q*OUTWC + (NXC-1)]*S2i[q*64+t];
    }
    ae[t]=s1; ai[t]=s2; red[t]=tr*wvi[t];
  }
  __syncthreads();
  if (t==0){ float s=0.f; for(int r=0;r<64;r++) s+=red[r]; fluxg[2]=s; }
  __syncthreads();
  if (t<64){
    float y1=0.f,y2=0.f;
    for (int q=0;q<64;q++){ y1 += Ge[t*64+q]*ae[q]; y2 += Gi[t*64+q]*ai[q]; }
    float f3 = fluxg[2];
    Xnge[t] = 1.0f *DXf*DVf*y1 + f3*XGe[t];
    Xngi[t] = 0.04f*DXf*DVf*y2 + f3*XGi[t];
  }
}

// ---------------- rho ----------------
__global__ __launch_bounds__(256) void k_rho(const float* __restrict__ Xe, int pe,
                                             const float* __restrict__ Xi, int pi,
                                             const float* __restrict__ ae, const float* __restrict__ ai,
                                             float* __restrict__ rho){
  int x = blockIdx.x*256 + threadIdx.x;
  float s = 0.f;
  for (int r=0;r<64;r++) s += ai[r]*Xi[(size_t)r*pi + x] - ae[r]*Xe[(size_t)r*pe + x];
  rho[x] = DVf*s;
}

// ---------------- poisson ----------------
__global__ __launch_bounds__(1024) void k_poisson(const float* __restrict__ rho, float* __restrict__ E){
  __shared__ float wsum[16];
  __shared__ float bsum[16];
  int t = threadIdx.x;
  int base = t*32;
  float loc[32];
  float run = 0.f;
  #pragma unroll
  for (int i=0;i<32;i++){ run += rho[base+i]; loc[i]=run; }
  float v = run;
  for (int off=1; off<64; off<<=1){
    float u = __shfl_up(v, off, 64);
    if ((t&63) >= off) v += u;
  }
  int wave = t>>6;
  if ((t&63)==63) wsum[wave] = v;
  __syncthreads();
  if (t==0){
    float a=0.f;
    for (int w0=0;w0<16;w0++){ float x=wsum[w0]; wsum[w0]=a; a+=x; }
  }
  __syncthreads();
  float offset = wsum[wave] + (v - run);
  float msum = 0.f;
  #pragma unroll
  for (int i=0;i<32;i++){ float e = DXf*(offset + loc[i]); loc[i]=e; msum += e; }
  float rs = msum;
  for (int off=32; off>0; off>>=1) rs += __shfl_down(rs, off, 64);
  if ((t&63)==0) bsum[wave]=rs;
  __syncthreads();
  if (t==0){ float a=0.f; for(int w0=0;w0<16;w0++) a+=bsum[w0]; bsum[0]=a; }
  __syncthreads();
  float mean = bsum[0]/(float)NXC;
  #pragma unroll
  for (int i=0;i<32;i++) E[base+i] = loc[i]-mean;
}

// ---------------- K step (fused species) ----------------
struct KArg { const float *X, *S, *VD, *Vl, *Vr; float nu, fac; float* Kout; };
__global__ __launch_bounds__(256) void k_kstepf(KArg k0, KArg k1,
    const float* __restrict__ E, const float* __restrict__ gsh, const float* __restrict__ fluxg)
{
  KArg A = blockIdx.y ? k1 : k0;
  __shared__ float Xt[64][66];
  __shared__ float Kt[64][66];
  const float* vpm = A.VD + 8192;
  const float* vmm = A.VD + 12288;
  const float* sV  = A.VD + 16384;
  const float* VMv = A.VD + 16448;
  int x0 = blockIdx.x*64;
  int tid = threadIdx.x;
  for (int i=tid;i<64*66;i+=256){
    int r = i/66, cc = i%66;
    int x = x0 - 1 + cc;
    Xt[r][cc] = (x>=0 && x<NXC)? A.X[(size_t)r*NXC + x] : 0.f;
  }
  __syncthreads();
  for (int i=tid;i<64*66;i+=256){
    int q = i/66, cc = i%66;
    float a = 0.f;
    for (int p=0;p<64;p++) a += A.S[p*64+q]*Xt[p][cc];
    Kt[q][cc] = a;
  }
  __syncthreads();
  float fo = fluxg[0];
  const float DTDX = DTf/DXf;
  for (int i=tid;i<4096;i+=256){
    int r = i>>6, xl = i&63;
    int cc = xl+1, x = x0+xl;
    float Ex = A.fac*E[x];
    float ep = Ex>0.f?Ex:0.f, em = Ex<0.f?Ex:0.f;
    float acc=0.f, nacc=0.f;
    for (int q=0;q<64;q++){
      float kk0=Kt[q][cc], km=Kt[q][cc-1], kp=Kt[q][cc+1];
      float vp_=vpm[r*64+q], vm_=vmm[r*64+q];
      float c0 = -DTDX*(vp_ - vm_) - DTf*(ep*A.Vl[r*64+q] + em*A.Vr[r*64+q]);
      acc += c0*kk0 + DTDX*(vp_*km - vm_*kp);
      nacc += sV[q]*kk0;
    }
    float y = Kt[r][cc]*(1.f - DTf*A.nu) + acc + DTf*(nacc*DVf*A.nu + fo*gsh[x])*VMv[r];
    A.Kout[(size_t)r*NXC + x] = y;
  }
}

// ---------------- L step (fused species) ----------------
struct LArg { const float *V, *S2, *ED, *XD, *Xng; float nu, Amax; float* Lout; };
__global__ __launch_bounds__(256) void k_lstepf(LArg l0, LArg l1)
{
  LArg A = blockIdx.y ? l1 : l0;
  __shared__ float Vt[64][66];
  __shared__ float Lt[64][66];
  const float* Ep = A.ED; const float* Em = A.ED+4096;
  const float* G = A.XD; const float* H = A.XD+4096;
  int v0 = blockIdx.x*64;
  int tid = threadIdx.x;
  for (int i=tid;i<64*66;i+=256){
    int r=i/66, cc=i%66; int vv=v0-1+cc;
    Vt[r][cc] = (vv>=0 && vv<NVC)? A.V[(size_t)r*NVC + vv] : 0.f;
  }
  __syncthreads();
  for (int i=tid;i<64*66;i+=256){
    int r=i/66, cc=i%66;
    float a=0.f;
    for (int q=0;q<64;q++) a += A.S2[r*64+q]*Vt[q][cc];
    Lt[r][cc]=a;
  }
  __syncthreads();
  const float DTDV = DTf/DVf;
  float fm = sqrtf(A.Amax*INV2PI);
  for (int i=tid;i<4096;i+=256){
    int r=i>>6, vl=i&63;
    int cc=vl+1, vgl=v0+vl;
    float vs = -VMAXf + (vgl+0.5f)*DVf;
    float vp = vs>0.f?vs:0.f, vm = vs<0.f?vs:0.f;
    float acc=0.f;
    for (int q=0;q<64;q++){
      float l0v=Lt[q][cc], lm=Lt[q][cc-1], lp=Lt[q][cc+1];
      float g=G[r*64+q], h=H[r*64+q], ht=H[q*64+r];
      float ep=Ep[r*64+q], em=Em[r*64+q];
      float c0 = -DTf*(vp*(g-h) + vm*(ht-g) + A.nu*DXf*g) - DTDV*(ep-em);
      acc += c0*l0v + DTDV*(ep*lm - em*lp);
    }
    float mv = fm*expf(-0.5f*A.Amax*vs*vs);
    float y = Lt[r][cc] + acc + DTf*A.Xng[r]*mv;
    A.Lout[(size_t)r*NVC + vgl] = y;
  }
}

// ---------------- S step ----------------
struct SArgs {
  const float *S, *XD, *ED, *VD, *Vl, *Vr, *avec;
  float *S2;
  float nu;
};
__global__ __launch_bounds__(256) void k_sstep(SArgs ea, SArgs ia, const float* __restrict__ fluxg){
  SArgs A = (blockIdx.x==0)? ea : ia;
  const float* G = A.XD; const float* H = A.XD+4096; const float* XG = A.XD+8192;
  const float* Ep = A.ED; const float* Em = A.ED+4096;
  const float* vpm = A.VD+8192; const float* vmm = A.VD+12288; const float* VMv = A.VD+16448;
  __shared__ float Sl[64*65];
  __shared__ float Tt[64*65];
  __shared__ float ACC[64*65];
  __shared__ float xng[64];
  int tid = threadIdx.x;
  for (int i=tid;i<4096;i+=256) Sl[(i>>6)*65+(i&63)] = A.S[i];
  __syncthreads();
  for (int i=tid;i<4096;i+=256){
    int a=i>>6,b=i&63; float s=0.f;
    for (int c=0;c<64;c++) s += (G[a*64+c]-H[a*64+c])*Sl[c*65+b];
    Tt[a*65+b]=s;
  }
  __syncthreads();
  for (int i=tid;i<4096;i+=256){
    int a=i>>6,b=i&63; float s=0.f;
    for (int c=0;c<64;c++) s += Tt[a*65+c]*vpm[c*64+b];
    ACC[a*65+b]=s;
  }
  __syncthreads();
  for (int i=tid;i<4096;i+=256){
    int a=i>>6,b=i&63; float s=0.f;
    for (int c=0;c<64;c++) s += (H[c*64+a]-G[a*64+c])*Sl[c*65+b];
    Tt[a*65+b]=s;
  }
  __syncthreads();
  for (int i=tid;i<4096;i+=256){
    int a=i>>6,b=i&63; float s=0.f;
    for (int c=0;c<64;c++) s += Tt[a*65+c]*vmm[c*64+b];
    ACC[a*65+b]+=s;
  }
  __syncthreads();
  for (int i=tid;i<4096;i+=256){
    int a=i>>6,b=i&63; float s=0.f;
    for (int c=0;c<64;c++) s += Ep[a*64+c]*Sl[c*65+b];
    Tt[a*65+b]=s;
  }
  __syncthreads();
  for (int i=tid;i<4096;i+=256){
    int a=i>>6,b=i&63; float s=0.f;
    for (int c=0;c<64;c++) s += Tt[a*65+c]*A.Vl[b*64+c];
    ACC[a*65+b]+=s;
  }
  __syncthreads();
  for (int i=tid;i<4096;i+=256){
    int a=i>>6,b=i&63; float s=0.f;
    for (int c=0;c<64;c++) s += Em[a*64+c]*Sl[c*65+b];
    Tt[a*65+b]=s;
  }
  __syncthreads();
  for (int i=tid;i<4096;i+=256){
    int a=i>>6,b=i&63; float s=0.f;
    for (int c=0;c<64;c++) s += Tt[a*65+c]*A.Vr[b*64+c];
    ACC[a*65+b]+=s;
  }
  if (tid<64){
    float y=0.f;
    for (int q=0;q<64;q++) y += G[tid*64+q]*A.avec[q];
    xng[tid] = A.nu*DXf*DVf*y + fluxg[1]*XG[tid];
  }
  __syncthreads();
  for (int i=tid;i<4096;i+=256){
    int a=i>>6,b=i&63; float s=0.f;
    for (int c=0;c<64;c++) s += G[a*64+c]*Sl[c*65+b];
    float accv = ACC[a*65+b] + A.nu*DXf*s - xng[a]*VMv[b];
    A.S2[i] = A.S[i] + DTf*accv;
  }
}

// ---------------- Gram (fused, fp64 partials) ----------------
__global__ __launch_bounds__(256) void k_gramf(const float* __restrict__ A0, const float* __restrict__ A1,
                                               int n, double* __restrict__ part){
  __shared__ float At[64][65];
  int sp = blockIdx.y;
  const float* A = sp ? A1 : A0;
  int blk = blockIdx.x, nb = gridDim.x;
  int chunk = n/nb;
  int c0b = blk*chunk;
  int tid=threadIdx.x, ta=tid>>4, tb=tid&15, a0=ta*4, b0=tb*4;
  double acc[4][4];
  #pragma unroll
  for (int ka=0;ka<4;ka++){
    #pragma unroll
    for (int kb=0;kb<4;kb++) acc[ka][kb]=0.0;
  }
  for (int t0=0;t0<chunk;t0+=64){
    int c0=c0b+t0;
    for (int i=tid;i<64*64;i+=256){ int r=i>>6, cc=i&63; At[r][cc]=A[(size_t)r*n + c0+cc]; }
    __syncthreads();
    for (int cc=0;cc<64;cc++){
      float av[4],bv[4];
      #pragma unroll
      for(int k=0;k<4;k++){ av[k]=At[a0+k][cc]; bv[k]=At[b0+k][cc]; }
      #pragma unroll
      for(int ka=0;ka<4;ka++){
        #pragma unroll
        for(int kb=0;kb<4;kb++) acc[ka][kb] += (double)av[ka]*(double)bv[kb];
      }
    }
    __syncthreads();
  }
  double* pb = part + (size_t)(sp*nb+blk)*4096;
  #pragma unroll
  for(int ka=0;ka<4;ka++){
    #pragma unroll
    for(int kb=0;kb<4;kb++) pb[(a0+ka)*64 + b0+kb] = acc[ka][kb];
  }
}

// ---------------- parallel Cholesky (upper, 64x64, stride-65 double) ----------------
__device__ inline void chol_par(double* M, int tid){
  for (int k=0;k<64;k++){
    if (tid<64){
      double v = M[k*65+tid];
      double pv = __shfl(v, k, 64);
      double dk = sqrt(pv > 0.0 ? pv : 1e-300);
      if (tid==k) M[k*65+k] = dk;
      else if (tid>k) M[k*65+tid] = v/dk;
    }
    __syncthreads();
    for (int i=(k+1)*64 + tid; i<4096; i+=256){
      int r=i>>6, c=i&63;
      if (c>=r) M[r*65+c] -= M[k*65+r]*M[k*65+c];
    }
    __syncthreads();
  }
}

// ---------------- fused QR: chol + inverse + bottom-chol + register Householder ----------------
struct QArgs {
  const double* Gd; const float* A; int n;
  float scaleS, invQ;
  float* SolveM; float* Sout; int outPitch; int mode;
};
__global__ __launch_bounds__(256) void k_qr(QArgs q0, QArgs q1){
  QArgs Q = (blockIdx.x==0)? q0 : q1;
  __shared__ double Lg[64*65];
  __shared__ float  Lw[64*65];
  __shared__ float  Rcf[64*64];
  __shared__ float  Atf[64*65];
  __shared__ double Td[32*33];
  __shared__ float  vbuf[4*33];
  __shared__ float  Dv[64];
  __shared__ float  sred[2];
  int tid = threadIdx.x;
  for (int i=tid;i<4096;i+=256) Lg[(i>>6)*65 + (i&63)] = Q.Gd[i];
  __syncthreads();
  chol_par(Lg, tid);                         // Lg upper = R (G = R^T R)
  // save R (float), stage Atop, invert diagonal 32-blocks of R
  for (int i=tid;i<4096;i+=256){ int r=i>>6,c=i&63; Rcf[i] = (c>=r)? (float)Lg[r*65+c] : 0.f; }
  for (int i=tid;i<4096;i+=256){ int c=i>>6,x=i&63; Atf[c*65+x] = Q.A[(size_t)c*Q.n + x]; }
  if (tid<64){
    int c=tid, b0=c&~31;
    Lw[c*65+c] = (float)(1.0/Lg[c*65+c]);
    for (int r=c-1;r>=b0;r--){
      double s=0.0;
      for (int j=r+1;j<=c;j++) s += Lg[r*65+j]*(double)Lw[j*65+c];
      Lw[r*65+c] = (float)(-s/Lg[r*65+r]);
    }
    for (int r=c+1;r<b0+32;r++) Lw[r*65+c]=0.f;
    if (b0==0){ for (int r=32;r<64;r++) Lw[r*65+c]=0.f; }
  }
  __syncthreads();
  // T = R12 @ W22
  for (int i=tid;i<1024;i+=256){
    int r=i>>5, c=32+(i&31);
    double s=0.0;
    for (int j=32;j<64;j++) s += Lg[r*65+j]*(double)Lw[j*65+c];
    Td[(i>>5)*33+(i&31)] = s;
  }
  __syncthreads();
  // W12 = -W11 @ T
  for (int i=tid;i<1024;i+=256){
    int r=i>>5, c=i&31;
    double s=0.0;
    for (int j=r;j<32;j++) s += (double)Lw[r*65+j]*Td[j*33+c];
    Lw[r*65+32+c] = (float)(-s);
  }
  __syncthreads();
  // Gbot = G - Atop^T Atop  -> Lg
  for (int i=tid;i<4096;i+=256){
    int r=i>>6, c=i&63;
    double s = Q.Gd[i];
    for (int x=0;x<64;x++) s -= (double)Atf[r*65+x]*(double)Atf[c*65+x];
    Lg[r*65+c] = s;
  }
  __syncthreads();
  chol_par(Lg, tid);                         // Lg upper = C (Gbot = C^T C)
  // ---- Householder on [Atop ; C] (128x64), columns in registers ----
  int col = tid>>2, l4 = tid&3;
  int rbase = l4*32;
  float a[32];
  if (l4 < 2){
    #pragma unroll
    for (int j=0;j<32;j++) a[j] = Atf[col*65 + rbase + j];
  } else {
    #pragma unroll
    for (int j=0;j<32;j++){
      int r = rbase - 64 + j;
      a[j] = (col>=r)? (float)Lg[r*65+col] : 0.f;
    }
  }
  __syncthreads();
  for (int k=0;k<64;k++){
    if (col==k){
      float sg=0.f, al=0.f;
      #pragma unroll
      for (int j=0;j<32;j++){
        int row = rbase+j;
        float v = (row>=k)? a[j] : 0.f;
        sg += v*v;
        al += (row==k)? a[j] : 0.f;
      }
      sg += __shfl_xor(sg,1,64); sg += __shfl_xor(sg,2,64);
      al += __shfl_xor(al,1,64); al += __shfl_xor(al,2,64);
      float beta = (al >= 0.f)? -sqrtf(sg) : sqrtf(sg);
      float vk = al - beta;
      if (l4==0){ Dv[k] = (beta >= 0.f)? 1.f : -1.f; sred[0] = sg - al*beta; }
      #pragma unroll
      for (int j=0;j<32;j++){
        int row = rbase+j;
        float v = (row < k)? 0.f : ((row==k)? vk : a[j]);
        vbuf[l4*33+j] = v;
      }
    }
    __syncthreads();
    float vv = sred[0];
    float vj[32]; float s=0.f;
    #pragma unroll
    for (int j=0;j<32;j++){ vj[j] = vbuf[l4*33+j]; s += vj[j]*a[j]; }
    s += __shfl_xor(s,1,64); s += __shfl_xor(s,2,64);
    if (col>k && vv > 0.f){
      float f = s/vv;
      #pragma unroll
      for (int j=0;j<32;j++) a[j] -= f*vj[j];
    }
    __syncthreads();
  }
  // outputs
  for (int i=tid;i<4096;i+=256){
    int r=i>>6, q2=i&63;
    Q.SolveM[i] = (q2<=r)? (Dv[r]*Lw[q2*65+r]*Q.invQ) : 0.f;
    if (Q.mode==0){
      Q.Sout[i] = (q2>=r)? (Dv[r]*Rcf[r*64+q2]*Q.scaleS) : 0.f;
    } else {
      Q.Sout[(size_t)r*Q.outPitch + q2] = (r>=q2)? (Dv[q2]*Rcf[q2*64+r]*Q.scaleS) : 0.f;
    }
  }
}

// ---------------- Q formation (fused species) ----------------
__global__ __launch_bounds__(256) void k_qformf(const float* __restrict__ A0, const float* __restrict__ A1,
    int n, const float* __restrict__ M0, const float* __restrict__ M1,
    float* __restrict__ O0, float* __restrict__ O1, int pitch)
{
  int sp = blockIdx.y >> 2;
  const float* A = sp ? A1 : A0;
  const float* M = sp ? M1 : M0;
  float* Out = sp ? O1 : O0;
  int x = blockIdx.x*256 + threadIdx.x;
  int r0 = (blockIdx.y & 3)*16;
  float acc[16];
  #pragma unroll
  for (int rr=0;rr<16;rr++) acc[rr]=0.f;
  for (int q=0;q<64;q++){
    float aq = A[(size_t)q*n + x];
    #pragma unroll
    for (int rr=0;rr<16;rr++) acc[rr] += M[(r0+rr)*64 + q]*aq;
  }
  #pragma unroll
  for (int rr=0;rr<16;rr++) Out[(size_t)(r0+rr)*pitch + x] = acc[rr];
}

// ======================= host =======================
extern "C" void kernel_launch(void* const* d_in, const int* in_sizes, int n_in,
                              void* d_out, int out_size, void* d_ws, size_t ws_size,
                              hipStream_t stream)
{
  (void)in_sizes; (void)n_in; (void)out_size; (void)ws_size;
  const float* Xe = (const float*)d_in[0];
  const float* Se = (const float*)d_in[1];
  const float* Ve = (const float*)d_in[2];
  const float* Xi = (const float*)d_in[3];
  const float* Si = (const float*)d_in[4];
  const float* Vi = (const float*)d_in[5];
  float* out = (float*)d_out;
  float* w = (float*)d_ws;

  size_t o = 0;
  auto alloc = [&](size_t nn){ size_t r=o; o += (nn+63)&~(size_t)63; return r; };
  size_t F_VD = alloc(2*PS_V);
  size_t F_XD = alloc(2*PS_X);
  size_t F_ED = alloc(2*PS_E);
  size_t F_VL_E = alloc(4096), F_VR_E = alloc(4096), F_VL_I = alloc(4096), F_VR_I = alloc(4096);
  size_t F_SC_E = alloc(4096), F_SC_I = alloc(4096), F_S2_E = alloc(4096), F_S2_I = alloc(4096);
  size_t F_SOLVE_E = alloc(4096), F_SOLVE_I = alloc(4096);
  size_t F_AE = alloc(64), F_AI = alloc(64), F_XNGE = alloc(64), F_XNGI = alloc(64);
  size_t F_FLUX = alloc(64);
  size_t F_GSH = alloc(NXC);
  size_t F_RHO = alloc(NXC);
  size_t F_E   = alloc(NXC);
  size_t F_KE = alloc((size_t)64*NXC);
  size_t F_KI = alloc((size_t)64*NXC);
  size_t F_LE = F_KE;
  size_t F_LI = F_KI;
  size_t F_PART = alloc(1060864);
  size_t F_GQR = alloc(16384);   // 8192 doubles (2 species)
  double* Gqr = (double*)(w + F_GQR);
  double* partd = (double*)(w + F_PART);
  float* part = w + F_PART;
  const float* VDe = w + F_VD;
  const float* VDi = w + F_VD + PS_V;
  const float* XDe = w + F_XD;
  const float* XDi = w + F_XD + PS_X;
  const float* EDe = w + F_ED;
  const float* EDi = w + F_ED + PS_E;

  float sqDX = sqrtf(DXf), isqDX = 1.f/sqrtf(DXf);
  float sqDV = sqrtf(DVf), isqDV = 1.f/sqrtf(DVf);
  const float NUE = 1.0f, NUI = 0.04f;
  const float FACE = -1.0f, FACI = 1.0f/1836.0f;

  // --- V-derived stats ---
  k_vstatsf<<<dim3(32,2),256,0,stream>>>(Ve, Vi, part);
  k_reduce32f<<<dim3((PS_V+255)/256,2),256,0,stream>>>(part, 32, PS_V, w+F_VD);
  k_gshape<<<1,1024,0,stream>>>(w+F_GSH);
  k_prep1<<<1,256,0,stream>>>(Ve, Vi, Se, Si, Xi, VDe, VDi,
                              w+F_VL_E, w+F_VR_E, w+F_VL_I, w+F_VR_I,
                              w+F_AE, w+F_AI, w+F_FLUX);
  // --- K step ---
  k_rho<<<NXC/256,256,0,stream>>>(Xe, NXC, Xi, NXC, w+F_AE, w+F_AI, w+F_RHO);
  k_poisson<<<1,1024,0,stream>>>(w+F_RHO, w+F_E);
  KArg ke{Xe, Se, VDe, w+F_VL_E, w+F_VR_E, NUE, FACE, w+F_KE};
  KArg ki{Xi, Si, VDi, w+F_VL_I, w+F_VR_I, NUI, FACI, w+F_KI};
  k_kstepf<<<dim3(NXC/64,2),256,0,stream>>>(ke, ki, w+F_E, w+F_GSH, w+F_FLUX);
  // --- QR of K^T (both species) ---
  k_gramf<<<dim3(64,2),256,0,stream>>>(w+F_KE, w+F_KI, NXC, partd);
  k_reduce64f<<<dim3(16,2),256,0,stream>>>(partd, 64, Gqr);
  {
    QArgs qe{Gqr,        w+F_KE, NXC, sqDX, isqDX, w+F_SOLVE_E, w+F_SC_E, 0, 0};
    QArgs qi{Gqr+4096,   w+F_KI, NXC, sqDX, isqDX, w+F_SOLVE_I, w+F_SC_I, 0, 0};
    k_qr<<<2,256,0,stream>>>(qe, qi);
  }
  k_qformf<<<dim3(NXC/256,8),256,0,stream>>>(w+F_KE, w+F_KI, NXC, w+F_SOLVE_E, w+F_SOLVE_I,
                                             out, out + (size_t)64*OUTWC, OUTWC);
  // --- X stats on new X ---
  k_xstatsf<<<dim3(64,2),256,0,stream>>>(out, out + (size_t)64*OUTWC, OUTWC, w+F_GSH, part);
  k_reduce32f<<<dim3((PS_X+255)/256,2),256,0,stream>>>(part, 64, PS_X, w+F_XD);
  // --- S step ---
  k_prep2<<<1,256,0,stream>>>(w+F_SC_E, w+F_SC_I, VDe, VDi, out + (size_t)64*OUTWC,
                              w+F_AE, w+F_AI, w+F_FLUX);
  k_rho<<<NXC/256,256,0,stream>>>(out, OUTWC, out + (size_t)64*OUTWC, OUTWC, w+F_AE, w+F_AI, w+F_RHO);
  k_poisson<<<1,1024,0,stream>>>(w+F_RHO, w+F_E);
  k_eweightf<<<dim3(64,2),256,0,stream>>>(out, out + (size_t)64*OUTWC, OUTWC, w+F_E, FACE, FACI, part);
  k_reduce32f<<<dim3((PS_E+255)/256,2),256,0,stream>>>(part, 64, PS_E, w+F_ED);
  SArgs ea; ea.S=w+F_SC_E; ea.XD=XDe; ea.ED=EDe; ea.VD=VDe; ea.Vl=w+F_VL_E; ea.Vr=w+F_VR_E; ea.avec=w+F_AE; ea.S2=w+F_S2_E; ea.nu=NUE;
  SArgs ia; ia.S=w+F_SC_I; ia.XD=XDi; ia.ED=EDi; ia.VD=VDi; ia.Vl=w+F_VL_I; ia.Vr=w+F_VR_I; ia.avec=w+F_AI; ia.S2=w+F_S2_I; ia.nu=NUI;
  k_sstep<<<2,256,0,stream>>>(ea, ia, w+F_FLUX);
  // --- L step ---
  k_prep3<<<1,256,0,stream>>>(w+F_S2_E, w+F_S2_I, VDe, VDi, out + (size_t)64*OUTWC,
                              XDe, XDi, w+F_AE, w+F_AI, w+F_XNGE, w+F_XNGI, w+F_FLUX);
  k_rho<<<NXC/256,256,0,stream>>>(out, OUTWC, out + (size_t)64*OUTWC, OUTWC, w+F_AE, w+F_AI, w+F_RHO);
  k_poisson<<<1,1024,0,stream>>>(w+F_RHO, w+F_E);
  k_eweightf<<<dim3(64,2),256,0,stream>>>(out, out + (size_t)64*OUTWC, OUTWC, w+F_E, FACE, FACI, part);
  k_reduce32f<<<dim3((PS_E+255)/256,2),256,0,stream>>>(part, 64, PS_E, w+F_ED);
  LArg le{Ve, w+F_S2_E, EDe, XDe, w+F_XNGE, NUE, 1.0f,    w+F_LE};
  LArg li{Vi, w+F_S2_I, EDi, XDi, w+F_XNGI, NUI, 1836.0f, w+F_LI};
  k_lstepf<<<dim3(NVC/64,2),256,0,stream>>>(le, li);
  // --- QR of L^T (both species) ---
  k_gramf<<<dim3(32,2),256,0,stream>>>(w+F_LE, w+F_LI, NVC, partd);
  k_reduce64f<<<dim3(16,2),256,0,stream>>>(partd, 32, Gqr);
  {
    QArgs qe{Gqr,      w+F_LE, NVC, sqDV, isqDV, w+F_SOLVE_E, out + NXC,                        OUTWC, 1};
    QArgs qi{Gqr+4096, w+F_LI, NVC, sqDV, isqDV, w+F_SOLVE_I, out + (size_t)64*OUTWC + NXC,     OUTWC, 1};
    k_qr<<<2,256,0,stream>>>(qe, qi);
  }
  k_qformf<<<dim3(NVC/256,8),256,0,stream>>>(w+F_LE, w+F_LI, NVC, w+F_SOLVE_E, w+F_SOLVE_I,
                                             out + NXC + 64, out + (size_t)64*OUTWC + NXC + 64, OUTWC);
}